// Round 15
// baseline (548.239 us; speedup 1.0000x reference)
//
#include <hip/hip_runtime.h>

typedef __bf16 bf16_t;
typedef __bf16 bf16x8 __attribute__((ext_vector_type(8)));
typedef __bf16 bf16x4 __attribute__((ext_vector_type(4)));
typedef float  f32x4  __attribute__((ext_vector_type(4)));
typedef float  f32x16 __attribute__((ext_vector_type(16)));

#define MFMA16(a,b,c) __builtin_amdgcn_mfma_f32_16x16x32_bf16((a),(b),(c),0,0,0)
#define MFMA32(a,b,c) __builtin_amdgcn_mfma_f32_32x32x16_bf16((a),(b),(c),0,0,0)
#define GLOBAL_AS __attribute__((address_space(1)))
#define LDS_AS    __attribute__((address_space(3)))
#define MEMFENCE  asm volatile("" ::: "memory")

// ---------- act LDS [64][512] bf16, rowB=1024B, XOR swizzle (row&15)<<4 ----------
__device__ __forceinline__ int act_off(int row, int kByte) {
    int byte = (row << 10) + kByte;
    return byte ^ ((row & 15) << 4);
}

// ---------- legacy swizzled helpers for attn kernel ((row&7)<<4) ----------
__device__ __forceinline__ bf16x8 lds_read8(const bf16_t* base, int row, int k, int rowB) {
    int byte = row * rowB + (k << 1);
    byte ^= ((row & 7) << 4);
    return *(const bf16x8*)((const char*)base + byte);
}
__device__ __forceinline__ void lds_write1(bf16_t* base, int row, int col, int rowB, float v) {
    int byte = row * rowB + (col << 1);
    byte ^= ((row & 7) << 4);
    *(bf16_t*)((char*)base + byte) = (bf16_t)v;
}
__device__ __forceinline__ void lds_write16B(bf16_t* base, int row, int colbyte, int rowB, bf16x8 v) {
    int byte = row * rowB + colbyte;
    byte ^= ((row & 7) << 4);
    *(bf16x8*)((char*)base + byte) = v;
}
__device__ __forceinline__ bf16x8 lds_read16B(const bf16_t* base, int row, int colbyte, int rowB) {
    int byte = row * rowB + colbyte;
    byte ^= ((row & 7) << 4);
    return *(const bf16x8*)((const char*)base + byte);
}

// ---------- W tile: BK=16, 16 KB, layout [kg(2)][col(512)][16B] ----------
__device__ __forceinline__ void gload_lds16(const void* g, void* l) {
    __builtin_amdgcn_global_load_lds((const GLOBAL_AS void*)g, (LDS_AS void*)l, 16, 0, 0);
}

// ---------- one K-step compute: wave tile 64 rows x 64 cols, MFMA32 acc[2][2] ----------
// acc[rr][cc][q*4+r] -> row = rr*32 + (lane&31), col = n0 + cc*32 + q*8 + (lane>>5)*4 + r
__device__ __forceinline__ void compute_step(f32x16 (&acc)[2][2],
    const bf16_t* act, const char* wbuf, int s, int n0, int l31, int kg)
{
    bf16x8 a[2], b[2];
#pragma unroll
    for (int cc = 0; cc < 2; ++cc)
        b[cc] = *(const bf16x8*)(wbuf + kg * 8192 + (n0 + cc * 32 + l31) * 16);
#pragma unroll
    for (int rr = 0; rr < 2; ++rr)
        a[rr] = *(const bf16x8*)((const char*)act + act_off(rr * 32 + l31, s * 32 + kg * 16));
#pragma unroll
    for (int rr = 0; rr < 2; ++rr)
#pragma unroll
        for (int cc = 0; cc < 2; ++cc)
            acc[rr][cc] = MFMA32(b[cc], a[rr], acc[rr][cc]);
}

// ---------- pipelined layer: single 16KB W-buffer + T14 reg-staged next tiles ----------
// Invariant entering loop: tile0 in wbuf (LANDED), pair P1 in regs (LANDED).
// Iter s: compute(s) || issue P_{s+2}; barrier; vmcnt(2) retires P_{s+1};
//         ds_write P_{s+1}; lgkmcnt(0); barrier.
template<int NS>
__device__ __forceinline__ void layer_rs(f32x16 (&acc)[2][2],
    const bf16_t* act, char* wbuf, const bf16_t* __restrict__ Wt,
    int t, int wave, int lane, int n0, int l31, int kg)
{
    const char* gb = (const char*)Wt;
    {   // prologue: tile0 -> LDS direct; tile1 -> regs; wait for BOTH (no ordering assumption)
        const char* s0 = gb + wave * 2048 + lane * 16;
        char* d0 = wbuf + wave * 2048;
        gload_lds16(s0, d0);
        gload_lds16(s0 + 1024, d0 + 1024);
    }
    MEMFENCE;
    uint4 rA0, rA1, rB0, rB1;
    rA0 = *(const uint4*)(gb + 16384 + t * 16);
    rA1 = *(const uint4*)(gb + 16384 + 8192 + t * 16);
    asm volatile("s_waitcnt vmcnt(0)" ::: "memory");   // tile0 in LDS AND P1 in regs
    __builtin_amdgcn_s_barrier();

#pragma unroll
    for (int p = 0; p < NS / 2; ++p) {
        {   // s = 2p, write pair = rA
            const int s = 2 * p;
            compute_step(acc, act, wbuf, s, n0, l31, kg);
            if (s + 2 < NS) {
                MEMFENCE;
                rB0 = *(const uint4*)(gb + (size_t)(s + 2) * 16384 + t * 16);
                rB1 = *(const uint4*)(gb + (size_t)(s + 2) * 16384 + 8192 + t * 16);
                MEMFENCE;
            }
            __builtin_amdgcn_s_barrier();              // all waves done reading wbuf
            if (s + 1 < NS) {
                asm volatile("s_waitcnt vmcnt(2)" ::: "memory");  // <=2 outstanding: P_{s+1} landed
                *(uint4*)(wbuf + t * 16) = rA0;
                *(uint4*)(wbuf + 8192 + t * 16) = rA1;
                asm volatile("s_waitcnt lgkmcnt(0)" ::: "memory");
            }
            __builtin_amdgcn_s_barrier();
        }
        {   // s = 2p+1, write pair = rB
            const int s = 2 * p + 1;
            compute_step(acc, act, wbuf, s, n0, l31, kg);
            if (s + 2 < NS) {
                MEMFENCE;
                rA0 = *(const uint4*)(gb + (size_t)(s + 2) * 16384 + t * 16);
                rA1 = *(const uint4*)(gb + (size_t)(s + 2) * 16384 + 8192 + t * 16);
                MEMFENCE;
            }
            __builtin_amdgcn_s_barrier();
            if (s + 1 < NS) {
                asm volatile("s_waitcnt vmcnt(2)" ::: "memory");
                *(uint4*)(wbuf + t * 16) = rB0;
                *(uint4*)(wbuf + 8192 + t * 16) = rB1;
                asm volatile("s_waitcnt lgkmcnt(0)" ::: "memory");
            }
            __builtin_amdgcn_s_barrier();
        }
    }
}

__device__ __forceinline__ void zero32(f32x16 (&acc)[2][2]) {
#pragma unroll
    for (int rr = 0; rr < 2; ++rr)
#pragma unroll
        for (int cc = 0; cc < 2; ++cc)
#pragma unroll
            for (int i = 0; i < 16; ++i) acc[rr][cc][i] = 0.f;
}

// ---------- epilogues ----------
template<bool RELU>
__device__ __forceinline__ void epi_lds32(const f32x16 (&acc)[2][2], const float* __restrict__ bias,
    bf16_t* act, int n0, int l31, int kg)
{
#pragma unroll
    for (int cc = 0; cc < 2; ++cc)
#pragma unroll
    for (int q = 0; q < 4; ++q) {
        const int c0 = n0 + cc * 32 + q * 8 + kg * 4;
        float4 b4 = *(const float4*)(bias + c0);
#pragma unroll
        for (int rr = 0; rr < 2; ++rr) {
            float v0 = acc[rr][cc][q * 4 + 0] + b4.x;
            float v1 = acc[rr][cc][q * 4 + 1] + b4.y;
            float v2 = acc[rr][cc][q * 4 + 2] + b4.z;
            float v3 = acc[rr][cc][q * 4 + 3] + b4.w;
            if (RELU) {
                v0 = fmaxf(v0, 0.f); v1 = fmaxf(v1, 0.f);
                v2 = fmaxf(v2, 0.f); v3 = fmaxf(v3, 0.f);
            }
            bf16x4 p = { (bf16_t)v0, (bf16_t)v1, (bf16_t)v2, (bf16_t)v3 };
            *(bf16x4*)((char*)act + act_off(rr * 32 + l31, c0 * 2)) = p;
        }
    }
}
__device__ __forceinline__ void epi_global32(const f32x16 (&acc)[2][2], const float* __restrict__ bias,
    float* __restrict__ out, long r0, int n0, int l31, int kg)
{
#pragma unroll
    for (int cc = 0; cc < 2; ++cc)
#pragma unroll
    for (int q = 0; q < 4; ++q) {
        const int c0 = n0 + cc * 32 + q * 8 + kg * 4;
        float4 b4 = *(const float4*)(bias + c0);
#pragma unroll
        for (int rr = 0; rr < 2; ++rr) {
            float4 o = { acc[rr][cc][q * 4 + 0] + b4.x, acc[rr][cc][q * 4 + 1] + b4.y,
                         acc[rr][cc][q * 4 + 2] + b4.z, acc[rr][cc][q * 4 + 3] + b4.w };
            *(float4*)(out + (r0 + rr * 32 + l31) * 512 + c0) = o;
        }
    }
}

// ---------- kernel 1: cast + retile weights to bf16 into ws (BK=16 layout) ----------
__device__ __forceinline__ void decode16(int m, int& n, int& k) {
    int s = m >> 13, r = m & 8191;
    int kg = r >> 12, q = r & 4095;
    n = q >> 3;
    k = (s << 4) + (kg << 3) + (q & 7);
}
__global__ __launch_bounds__(256) void cast_kernel(
    const float* __restrict__ W1, const float* __restrict__ W2,
    const float* __restrict__ muW, const float* __restrict__ lvW,
    const float* __restrict__ Wqkv, const float* __restrict__ Wo,
    const float* __restrict__ Wc, const float* __restrict__ Wd1,
    const float* __restrict__ Wd2, const float* __restrict__ Wd3,
    bf16_t* __restrict__ dst)
{
    int i = blockIdx.x * 256 + threadIdx.x;   // grid exactly covers 1376256
    float val;
    int n, k;
    if (i < 262144) {
        decode16(i, n, k);                    val = W1[n * 512 + k];
    } else if (i < 524288) {
        decode16(i - 262144, n, k);           val = W2[n * 512 + k];
    } else if (i < 786432) {
        decode16(i - 524288, n, k);
        val = (n < 256) ? muW[n * 512 + k] : lvW[(n - 256) * 512 + k];
    } else if (i < 798720) { val = Wqkv[i - 786432]; }
    else if (i < 802816)   { val = Wo[i - 798720]; }
    else if (i < 819200)   { val = Wc[i - 802816]; }
    else if (i < 851968) {
        decode16(i - 819200, n, k);           val = Wd1[n * 64 + k];
    } else if (i < 1114112) {
        decode16(i - 851968, n, k);           val = Wd2[n * 512 + k];
    } else {
        decode16(i - 1114112, n, k);          val = Wd3[n * 512 + k];
    }
    dst[i] = (bf16_t)val;
}

// ---------- kernel 2: encoder + heads + reparameterize (64-row, 80 KB, 2 blk/CU) ----------
__global__ __launch_bounds__(512, 4) void enc_kernel(
    const float* __restrict__ x, const float* __restrict__ eps,
    const bf16_t* __restrict__ W1t, const float* __restrict__ b1,
    const bf16_t* __restrict__ W2t, const float* __restrict__ b2,
    const bf16_t* __restrict__ Ht,  const float* __restrict__ mub,
    const float* __restrict__ lvb,  bf16_t* __restrict__ zout)
{
    __shared__ bf16_t act[64 * 512];             // 64 KB
    __shared__ alignas(16) char wbuf[16384];     // 16 KB
    const int t = threadIdx.x;
    const int wave = t >> 6, lane = t & 63, l31 = lane & 31, kg = lane >> 5;
    const int n0 = wave * 64;
    const size_t r0 = (size_t)blockIdx.x * 64;

    // stage x tile (fp32 -> bf16, swizzled)
    for (int it = 0; it < 16; ++it) {
        int flat = it * 512 + t;
        int row = flat >> 7, c4 = flat & 127;
        float4 v = ((const float4*)(x + (r0 + row) * 512))[c4];
        bf16x4 h = { (bf16_t)v.x, (bf16_t)v.y, (bf16_t)v.z, (bf16_t)v.w };
        *(bf16x4*)((char*)act + act_off(row, c4 * 8)) = h;
    }
    asm volatile("s_waitcnt lgkmcnt(0)" ::: "memory");

    f32x16 acc[2][2];
    zero32(acc);
    layer_rs<32>(acc, act, wbuf, W1t, t, wave, lane, n0, l31, kg);
    epi_lds32<true>(acc, b1, act, n0, l31, kg);
    asm volatile("s_waitcnt lgkmcnt(0)" ::: "memory");
    __builtin_amdgcn_s_barrier();

    zero32(acc);
    layer_rs<32>(acc, act, wbuf, W2t, t, wave, lane, n0, l31, kg);
    epi_lds32<true>(acc, b2, act, n0, l31, kg);
    asm volatile("s_waitcnt lgkmcnt(0)" ::: "memory");
    __builtin_amdgcn_s_barrier();

    zero32(acc);
    layer_rs<32>(acc, act, wbuf, Ht, t, wave, lane, n0, l31, kg);
    epi_lds32<false>(acc, (n0 < 256) ? mub : (lvb - 256), act, n0, l31, kg);
    asm volatile("s_waitcnt lgkmcnt(0)" ::: "memory");
    __builtin_amdgcn_s_barrier();

    // z = mu + eps * T^1.5 * exp(0.5*lv); mu cols 0-255, lv cols 256-511
    const int ce = (t & 63) * 4;
    const int ag = ce >> 6;
    const float tp = (ag == 0) ? 1.8371173070873836f
                   : (ag == 1) ? 0.35355339059327373f
                   : (ag == 2) ? 1.0f
                               : 0.7155417527999327f;
    const int rb = t >> 6;
    for (int it = 0; it < 8; ++it) {
        int row = it * 8 + rb;
        bf16x4 mu4 = *(const bf16x4*)((const char*)act + act_off(row, ce * 2));
        bf16x4 lv4 = *(const bf16x4*)((const char*)act + act_off(row, (ce + 256) * 2));
        float4 ep4 = *(const float4*)(eps + (r0 + row) * 256 + ce);
        bf16x4 zo;
        zo[0] = (bf16_t)fmaf(ep4.x * tp, expf(0.5f * (float)lv4[0]), (float)mu4[0]);
        zo[1] = (bf16_t)fmaf(ep4.y * tp, expf(0.5f * (float)lv4[1]), (float)mu4[1]);
        zo[2] = (bf16_t)fmaf(ep4.z * tp, expf(0.5f * (float)lv4[2]), (float)mu4[2]);
        zo[3] = (bf16_t)fmaf(ep4.w * tp, expf(0.5f * (float)lv4[3]), (float)mu4[3]);
        *(bf16x4*)(zout + (r0 + row) * 256 + ce) = zo;
    }
}

// ---------- kernel 3: attention over 4 agents + consensus (unchanged) ----------
__global__ __launch_bounds__(512) void attn_kernel(
    const bf16_t* __restrict__ z,
    const bf16_t* __restrict__ Wqkvb, const float* __restrict__ bqkv,
    const bf16_t* __restrict__ Wob,   const float* __restrict__ bo,
    const bf16_t* __restrict__ Wcb,   const float* __restrict__ bc,
    bf16_t* __restrict__ zcb)
{
    __shared__ bf16_t zt[256 * 64];    // z tile, later ctx tile   (rowB 128)
    __shared__ bf16_t qt[256 * 192];   // qkv tile, later z_att    (rowB 384/128)
    const int t = threadIdx.x;
    const size_t s0 = (size_t)blockIdx.x * 64;

    for (int it = 0; it < 4; ++it) {
        int ch = it * 512 + t;
        int r = ch >> 3, cc = ch & 7;
        bf16x8 v = *(const bf16x8*)(z + s0 * 256 + r * 64 + cc * 8);
        lds_write16B(zt, r, cc * 16, 128, v);
    }
    __syncthreads();
    const int wave = t >> 6, lane = t & 63, l15 = lane & 15, lhi = lane >> 4;
    const int rbase = wave * 32;

    for (int cc = 0; cc < 4; ++cc) {
        f32x4 acc[2][3] = {};
#pragma unroll
        for (int ks = 0; ks < 2; ++ks) {
            int k = ks * 32 + lhi * 8;
            bf16x8 a0 = lds_read8(zt, rbase + l15, k, 128);
            bf16x8 a1 = lds_read8(zt, rbase + 16 + l15, k, 128);
#pragma unroll
            for (int cf = 0; cf < 3; ++cf) {
                bf16x8 b = *(const bf16x8*)(Wqkvb + (cc * 48 + cf * 16 + l15) * 64 + k);
                acc[0][cf] = MFMA16(a0, b, acc[0][cf]);
                acc[1][cf] = MFMA16(a1, b, acc[1][cf]);
            }
        }
#pragma unroll
        for (int cf = 0; cf < 3; ++cf) {
            int col = cc * 48 + cf * 16 + l15;
            float bs = bqkv[col];
#pragma unroll
            for (int rf = 0; rf < 2; ++rf)
#pragma unroll
                for (int r = 0; r < 4; ++r)
                    lds_write1(qt, rbase + rf * 16 + lhi * 4 + r, col, 384, acc[rf][cf][r] + bs);
        }
    }
    __syncthreads();

    if (t < 256) {
        const int sl = t >> 2, head = t & 3;
        bf16x8 qv[4][2], kv[4][2], vv[4][2];
#pragma unroll
        for (int a2 = 0; a2 < 4; ++a2) {
            int r = sl * 4 + a2;
#pragma unroll
            for (int i = 0; i < 2; ++i) {
                qv[a2][i] = lds_read16B(qt, r, head * 32 + 16 * i, 384);
                kv[a2][i] = lds_read16B(qt, r, 128 + head * 32 + 16 * i, 384);
                vv[a2][i] = lds_read16B(qt, r, 256 + head * 32 + 16 * i, 384);
            }
        }
        float sc[4][4];
#pragma unroll
        for (int qa = 0; qa < 4; ++qa)
#pragma unroll
            for (int ka = 0; ka < 4; ++ka) {
                float s = 0.f;
#pragma unroll
                for (int i = 0; i < 2; ++i)
#pragma unroll
                    for (int j = 0; j < 8; ++j)
                        s += (float)qv[qa][i][j] * (float)kv[ka][i][j];
                sc[qa][ka] = s * 0.25f;
            }
#pragma unroll
        for (int qa = 0; qa < 4; ++qa) {
            float m = fmaxf(fmaxf(sc[qa][0], sc[qa][1]), fmaxf(sc[qa][2], sc[qa][3]));
            float e[4], sum = 0.f;
#pragma unroll
            for (int ka = 0; ka < 4; ++ka) { e[ka] = expf(sc[qa][ka] - m); sum += e[ka]; }
            float inv = 1.f / sum;
#pragma unroll
            for (int i = 0; i < 2; ++i) {
                bf16x8 cv;
#pragma unroll
                for (int j = 0; j < 8; ++j) {
                    float cval = 0.f;
#pragma unroll
                    for (int ka = 0; ka < 4; ++ka) cval += e[ka] * inv * (float)vv[ka][i][j];
                    cv[j] = (bf16_t)cval;
                }
                lds_write16B(zt, sl * 4 + qa, head * 32 + 16 * i, 128, cv);
            }
        }
    }
    __syncthreads();

    {   // z_att = ctx @ Wo^T + bo
        f32x4 acc[2][4] = {};
#pragma unroll
        for (int ks = 0; ks < 2; ++ks) {
            int k = ks * 32 + lhi * 8;
            bf16x8 a0 = lds_read8(zt, rbase + l15, k, 128);
            bf16x8 a1 = lds_read8(zt, rbase + 16 + l15, k, 128);
#pragma unroll
            for (int cf = 0; cf < 4; ++cf) {
                bf16x8 b = *(const bf16x8*)(Wob + (cf * 16 + l15) * 64 + k);
                acc[0][cf] = MFMA16(a0, b, acc[0][cf]);
                acc[1][cf] = MFMA16(a1, b, acc[1][cf]);
            }
        }
        __syncthreads();
#pragma unroll
        for (int cf = 0; cf < 4; ++cf) {
            int col = cf * 16 + l15;
            float bs = bo[col];
#pragma unroll
            for (int rf = 0; rf < 2; ++rf)
#pragma unroll
                for (int r = 0; r < 4; ++r)
                    lds_write1(qt, rbase + rf * 16 + lhi * 4 + r, col, 128, acc[rf][cf][r] + bs);
        }
    }
    __syncthreads();

    {   // z_consensus = z_att.reshape(64,256) @ Wc^T + bc
        f32x4 acc2[2] = {};
        const int rfw = wave >> 1, cbase = (wave & 1) * 2;
        const int srow = rfw * 16 + l15;
#pragma unroll
        for (int ks = 0; ks < 8; ++ks) {
            int k = ks * 32 + lhi * 8;
            int byte = (srow << 9) + (k << 1);
            byte ^= ((((srow << 2) + (k >> 6)) & 7) << 4);
            bf16x8 a = *(const bf16x8*)((const char*)qt + byte);
#pragma unroll
            for (int i = 0; i < 2; ++i) {
                bf16x8 b = *(const bf16x8*)(Wcb + ((cbase + i) * 16 + l15) * 256 + k);
                acc2[i] = MFMA16(a, b, acc2[i]);
            }
        }
#pragma unroll
        for (int i = 0; i < 2; ++i) {
            int col = (cbase + i) * 16 + l15;
            float bs = bc[col];
#pragma unroll
            for (int r = 0; r < 4; ++r) {
                int s = (int)(s0) + rfw * 16 + lhi * 4 + r;
                zcb[(size_t)s * 64 + col] = (bf16_t)(acc2[i][r] + bs);
            }
        }
    }
}

// ---------- kernel 4: fused 3-layer decoder (64-row, 80 KB, 2 blk/CU) ----------
__global__ __launch_bounds__(512, 4) void dec_kernel(
    const bf16_t* __restrict__ z, const bf16_t* __restrict__ zc,
    const bf16_t* __restrict__ Wd1t, const float* __restrict__ bd1,
    const bf16_t* __restrict__ Wd2t, const float* __restrict__ bd2,
    const bf16_t* __restrict__ Wd3t, const float* __restrict__ bd3,
    float* __restrict__ out)
{
    __shared__ bf16_t act[64 * 512];             // 64 KB (latents in cols 0..63)
    __shared__ alignas(16) char wbuf[16384];     // 16 KB
    const int t = threadIdx.x;
    const int wave = t >> 6, lane = t & 63, l31 = lane & 31, kg = lane >> 5;
    const int n0 = wave * 64;
    const long r0 = (long)blockIdx.x * 64;

    {   // gather latent rows into act cols 0..63: row = s*5 + j
        int row = t >> 3, ch = t & 7;
        long rg = r0 + row;
        int s5 = (int)(rg / 5), j = (int)(rg - (long)s5 * 5);
        const bf16_t* src = (j == 0) ? (zc + (size_t)s5 * 64)
                                     : (z + (size_t)s5 * 256 + (j - 1) * 64);
        bf16x8 v = *(const bf16x8*)(src + ch * 8);
        *(bf16x8*)((char*)act + act_off(row, ch * 16)) = v;
    }
    asm volatile("s_waitcnt lgkmcnt(0)" ::: "memory");

    f32x16 acc[2][2];
    zero32(acc);
    layer_rs<4>(acc, act, wbuf, Wd1t, t, wave, lane, n0, l31, kg);
    epi_lds32<true>(acc, bd1, act, n0, l31, kg);
    asm volatile("s_waitcnt lgkmcnt(0)" ::: "memory");
    __builtin_amdgcn_s_barrier();

    zero32(acc);
    layer_rs<32>(acc, act, wbuf, Wd2t, t, wave, lane, n0, l31, kg);
    epi_lds32<true>(acc, bd2, act, n0, l31, kg);
    asm volatile("s_waitcnt lgkmcnt(0)" ::: "memory");
    __builtin_amdgcn_s_barrier();

    zero32(acc);
    layer_rs<32>(acc, act, wbuf, Wd3t, t, wave, lane, n0, l31, kg);
    epi_global32(acc, bd3, out, r0, n0, l31, kg);
}

// ---------- launcher ----------
extern "C" void kernel_launch(void* const* d_in, const int* in_sizes, int n_in,
                              void* d_out, int out_size, void* d_ws, size_t ws_size,
                              hipStream_t stream) {
    const float* x    = (const float*)d_in[0];
    const float* eps  = (const float*)d_in[1];
    const float* W1   = (const float*)d_in[2];
    const float* b1   = (const float*)d_in[3];
    const float* W2   = (const float*)d_in[4];
    const float* b2   = (const float*)d_in[5];
    const float* muW  = (const float*)d_in[6];
    const float* mub  = (const float*)d_in[7];
    const float* lvW  = (const float*)d_in[8];
    const float* lvb  = (const float*)d_in[9];
    const float* Wqkv = (const float*)d_in[10];
    const float* bqkv = (const float*)d_in[11];
    const float* Wo   = (const float*)d_in[12];
    const float* bo   = (const float*)d_in[13];
    const float* Wc   = (const float*)d_in[14];
    const float* bc   = (const float*)d_in[15];
    const float* Wd1  = (const float*)d_in[16];
    const float* bd1  = (const float*)d_in[17];
    const float* Wd2  = (const float*)d_in[18];
    const float* bd2  = (const float*)d_in[19];
    const float* Wd3  = (const float*)d_in[20];
    const float* bd3  = (const float*)d_in[21];
    float* out = (float*)d_out;

    bf16_t* wsb  = (bf16_t*)d_ws;
    bf16_t* W1t  = wsb + 0;
    bf16_t* W2t  = wsb + 262144;
    bf16_t* Ht   = wsb + 524288;    // [muW ; lvW] retiled
    bf16_t* Wqkvb= wsb + 786432;
    bf16_t* Wob  = wsb + 798720;
    bf16_t* Wcb  = wsb + 802816;
    bf16_t* Wd1t = wsb + 819200;
    bf16_t* Wd2t = wsb + 851968;
    bf16_t* Wd3t = wsb + 1114112;
    bf16_t* zbuf = wsb + 1376256;   // (B,256) bf16
    bf16_t* zcb  = wsb + 9764864;   // (B,64)  bf16

    cast_kernel<<<dim3(5376), dim3(256), 0, stream>>>(
        W1, W2, muW, lvW, Wqkv, Wo, Wc, Wd1, Wd2, Wd3, wsb);
    enc_kernel<<<dim3(512), dim3(512), 0, stream>>>(
        x, eps, W1t, b1, W2t, b2, Ht, mub, lvb, zbuf);
    attn_kernel<<<dim3(512), dim3(512), 0, stream>>>(
        zbuf, Wqkvb, bqkv, Wob, bo, Wcb, bc, zcb);
    dec_kernel<<<dim3(2560), dim3(512), 0, stream>>>(
        zbuf, zcb, Wd1t, bd1, Wd2t, bd2, Wd3t, bd3, out);
}

// Round 16
// 454.019 us; speedup vs baseline: 1.2075x; 1.2075x over previous
//
#include <hip/hip_runtime.h>

typedef __bf16 bf16_t;
typedef __bf16 bf16x8 __attribute__((ext_vector_type(8)));
typedef __bf16 bf16x4 __attribute__((ext_vector_type(4)));
typedef float  f32x4  __attribute__((ext_vector_type(4)));
typedef float  f32x16 __attribute__((ext_vector_type(16)));

#define MFMA16(a,b,c) __builtin_amdgcn_mfma_f32_16x16x32_bf16((a),(b),(c),0,0,0)
#define MFMA32(a,b,c) __builtin_amdgcn_mfma_f32_32x32x16_bf16((a),(b),(c),0,0,0)
#define GLOBAL_AS __attribute__((address_space(1)))
#define LDS_AS    __attribute__((address_space(3)))
#define MEMFENCE  asm volatile("" ::: "memory")

// ---------- act LDS [128][512] bf16, rowB=1024B, XOR swizzle (row&15)<<4 ----------
__device__ __forceinline__ int act_off(int row, int kByte) {
    int byte = (row << 10) + kByte;
    return byte ^ ((row & 15) << 4);
}

// ---------- legacy swizzled helpers for attn kernel ((row&7)<<4) ----------
__device__ __forceinline__ bf16x8 lds_read8(const bf16_t* base, int row, int k, int rowB) {
    int byte = row * rowB + (k << 1);
    byte ^= ((row & 7) << 4);
    return *(const bf16x8*)((const char*)base + byte);
}
__device__ __forceinline__ void lds_write1(bf16_t* base, int row, int col, int rowB, float v) {
    int byte = row * rowB + (col << 1);
    byte ^= ((row & 7) << 4);
    *(bf16_t*)((char*)base + byte) = (bf16_t)v;
}
__device__ __forceinline__ void lds_write16B(bf16_t* base, int row, int colbyte, int rowB, bf16x8 v) {
    int byte = row * rowB + colbyte;
    byte ^= ((row & 7) << 4);
    *(bf16x8*)((char*)base + byte) = v;
}
__device__ __forceinline__ bf16x8 lds_read16B(const bf16_t* base, int row, int colbyte, int rowB) {
    int byte = row * rowB + colbyte;
    byte ^= ((row & 7) << 4);
    return *(const bf16x8*)((const char*)base + byte);
}

// ---------- W tile: BK=16, 16 KB, layout [kg(2)][col(512)][16B] ----------
__device__ __forceinline__ void gload_lds16(const void* g, void* l) {
    __builtin_amdgcn_global_load_lds((const GLOBAL_AS void*)g, (LDS_AS void*)l, 16, 0, 0);
}

// ---------- one K-step: wave tile 64 rows x 128 cols, MFMA32 acc[2][4] ----------
// acc[rr][cc][q*4+r] -> row = wm*64 + rr*32 + (lane&31),
//                       col = wn*128 + cc*32 + q*8 + (lane>>5)*4 + r   (R13-verified)
__device__ __forceinline__ void compute_step(f32x16 (&acc)[2][4],
    const bf16_t* act, const char* wbuf, int s, int wm, int wn, int l31, int kg)
{
    bf16x8 a[2], b[4];
#pragma unroll
    for (int cc = 0; cc < 4; ++cc)
        b[cc] = *(const bf16x8*)(wbuf + kg * 8192 + (wn * 128 + cc * 32 + l31) * 16);
#pragma unroll
    for (int rr = 0; rr < 2; ++rr)
        a[rr] = *(const bf16x8*)((const char*)act +
                    act_off(wm * 64 + rr * 32 + l31, s * 32 + kg * 16));
#pragma unroll
    for (int rr = 0; rr < 2; ++rr)
#pragma unroll
        for (int cc = 0; cc < 4; ++cc)
            acc[rr][cc] = MFMA32(b[cc], a[rr], acc[rr][cc]);
}

// ---------- pipelined layer: 2x16KB LDS buffers + reg-staged tiles (T14) ----------
// Invariant entering loop: tile0 in wbuf[0] (LANDED), pair P1 in regs (LANDED).
// Step s: compute(s) || issue P_{s+2}; barrier; wait (vmcnt(2) steady / vmcnt(0) last);
//         ds_write P_{s+1}; lgkmcnt(0); barrier.
template<int NS>
__device__ __forceinline__ void layer_rs(f32x16 (&acc)[2][4],
    const bf16_t* act, char* wbuf, const bf16_t* __restrict__ Wt,
    int t, int wave, int lane, int wm, int wn, int l31, int kg)
{
    const char* gb = (const char*)Wt;
    {   // prologue: tile0 -> LDS direct; tile1 -> regs; wait for BOTH
        const char* s0 = gb + wave * 2048 + lane * 16;
        char* d0 = wbuf + wave * 2048;
        gload_lds16(s0, d0);
        gload_lds16(s0 + 1024, d0 + 1024);
    }
    MEMFENCE;
    uint4 rA0, rA1, rB0, rB1;
    rA0 = *(const uint4*)(gb + 16384 + t * 16);
    rA1 = *(const uint4*)(gb + 16384 + 8192 + t * 16);
    asm volatile("s_waitcnt vmcnt(0)" ::: "memory");
    __builtin_amdgcn_s_barrier();

#pragma unroll
    for (int p = 0; p < NS / 2; ++p) {
        {   // s = 2p, write pair = rA
            const int s = 2 * p;
            compute_step(acc, act, wbuf + (s & 1) * 16384, s, wm, wn, l31, kg);
            if (s + 2 < NS) {
                MEMFENCE;
                rB0 = *(const uint4*)(gb + (size_t)(s + 2) * 16384 + t * 16);
                rB1 = *(const uint4*)(gb + (size_t)(s + 2) * 16384 + 8192 + t * 16);
                MEMFENCE;
            }
            __builtin_amdgcn_s_barrier();
            if (s + 1 < NS) {
                if (s + 2 < NS) asm volatile("s_waitcnt vmcnt(2)" ::: "memory");
                else            asm volatile("s_waitcnt vmcnt(0)" ::: "memory");
                char* nb = wbuf + ((s + 1) & 1) * 16384;
                *(uint4*)(nb + t * 16) = rA0;
                *(uint4*)(nb + 8192 + t * 16) = rA1;
                asm volatile("s_waitcnt lgkmcnt(0)" ::: "memory");
            }
            __builtin_amdgcn_s_barrier();
        }
        {   // s = 2p+1, write pair = rB
            const int s = 2 * p + 1;
            compute_step(acc, act, wbuf + (s & 1) * 16384, s, wm, wn, l31, kg);
            if (s + 2 < NS) {
                MEMFENCE;
                rA0 = *(const uint4*)(gb + (size_t)(s + 2) * 16384 + t * 16);
                rA1 = *(const uint4*)(gb + (size_t)(s + 2) * 16384 + 8192 + t * 16);
                MEMFENCE;
            }
            __builtin_amdgcn_s_barrier();
            if (s + 1 < NS) {
                if (s + 2 < NS) asm volatile("s_waitcnt vmcnt(2)" ::: "memory");
                else            asm volatile("s_waitcnt vmcnt(0)" ::: "memory");
                char* nb = wbuf + ((s + 1) & 1) * 16384;
                *(uint4*)(nb + t * 16) = rB0;
                *(uint4*)(nb + 8192 + t * 16) = rB1;
                asm volatile("s_waitcnt lgkmcnt(0)" ::: "memory");
            }
            __builtin_amdgcn_s_barrier();
        }
    }
}

__device__ __forceinline__ void zero32(f32x16 (&acc)[2][4]) {
#pragma unroll
    for (int rr = 0; rr < 2; ++rr)
#pragma unroll
        for (int cc = 0; cc < 4; ++cc)
#pragma unroll
            for (int i = 0; i < 16; ++i) acc[rr][cc][i] = 0.f;
}

// ---------- epilogues (R13-verified mapping) ----------
template<bool RELU>
__device__ __forceinline__ void epi_lds32(const f32x16 (&acc)[2][4], const float* __restrict__ bias,
    bf16_t* act, int wm, int wn, int l31, int kg)
{
#pragma unroll
    for (int cc = 0; cc < 4; ++cc)
#pragma unroll
    for (int q = 0; q < 4; ++q) {
        const int c0 = wn * 128 + cc * 32 + q * 8 + kg * 4;
        float4 b4 = *(const float4*)(bias + c0);
#pragma unroll
        for (int rr = 0; rr < 2; ++rr) {
            float v0 = acc[rr][cc][q * 4 + 0] + b4.x;
            float v1 = acc[rr][cc][q * 4 + 1] + b4.y;
            float v2 = acc[rr][cc][q * 4 + 2] + b4.z;
            float v3 = acc[rr][cc][q * 4 + 3] + b4.w;
            if (RELU) {
                v0 = fmaxf(v0, 0.f); v1 = fmaxf(v1, 0.f);
                v2 = fmaxf(v2, 0.f); v3 = fmaxf(v3, 0.f);
            }
            bf16x4 p = { (bf16_t)v0, (bf16_t)v1, (bf16_t)v2, (bf16_t)v3 };
            *(bf16x4*)((char*)act + act_off(wm * 64 + rr * 32 + l31, c0 * 2)) = p;
        }
    }
}
__device__ __forceinline__ void epi_global32(const f32x16 (&acc)[2][4], const float* __restrict__ bias,
    float* __restrict__ out, long r0, int wm, int wn, int l31, int kg)
{
#pragma unroll
    for (int cc = 0; cc < 4; ++cc)
#pragma unroll
    for (int q = 0; q < 4; ++q) {
        const int c0 = wn * 128 + cc * 32 + q * 8 + kg * 4;
        float4 b4 = *(const float4*)(bias + c0);
#pragma unroll
        for (int rr = 0; rr < 2; ++rr) {
            float4 o = { acc[rr][cc][q * 4 + 0] + b4.x, acc[rr][cc][q * 4 + 1] + b4.y,
                         acc[rr][cc][q * 4 + 2] + b4.z, acc[rr][cc][q * 4 + 3] + b4.w };
            *(float4*)(out + (r0 + wm * 64 + rr * 32 + l31) * 512 + c0) = o;
        }
    }
}

// ---------- kernel 1: cast + retile weights to bf16 into ws (BK=16 layout) ----------
__device__ __forceinline__ void decode16(int m, int& n, int& k) {
    int s = m >> 13, r = m & 8191;
    int kg = r >> 12, q = r & 4095;
    n = q >> 3;
    k = (s << 4) + (kg << 3) + (q & 7);
}
__global__ __launch_bounds__(256) void cast_kernel(
    const float* __restrict__ W1, const float* __restrict__ W2,
    const float* __restrict__ muW, const float* __restrict__ lvW,
    const float* __restrict__ Wqkv, const float* __restrict__ Wo,
    const float* __restrict__ Wc, const float* __restrict__ Wd1,
    const float* __restrict__ Wd2, const float* __restrict__ Wd3,
    bf16_t* __restrict__ dst)
{
    int i = blockIdx.x * 256 + threadIdx.x;   // grid exactly covers 1376256
    float val;
    int n, k;
    if (i < 262144) {
        decode16(i, n, k);                    val = W1[n * 512 + k];
    } else if (i < 524288) {
        decode16(i - 262144, n, k);           val = W2[n * 512 + k];
    } else if (i < 786432) {
        decode16(i - 524288, n, k);
        val = (n < 256) ? muW[n * 512 + k] : lvW[(n - 256) * 512 + k];
    } else if (i < 798720) { val = Wqkv[i - 786432]; }
    else if (i < 802816)   { val = Wo[i - 798720]; }
    else if (i < 819200)   { val = Wc[i - 802816]; }
    else if (i < 851968) {
        decode16(i - 819200, n, k);           val = Wd1[n * 64 + k];
    } else if (i < 1114112) {
        decode16(i - 851968, n, k);           val = Wd2[n * 512 + k];
    } else {
        decode16(i - 1114112, n, k);          val = Wd3[n * 512 + k];
    }
    dst[i] = (bf16_t)val;
}

// ---------- kernel 2: encoder + heads + reparameterize (128-row, 160 KB) ----------
__global__ __launch_bounds__(512, 2) void enc_kernel(
    const float* __restrict__ x, const float* __restrict__ eps,
    const bf16_t* __restrict__ W1t, const float* __restrict__ b1,
    const bf16_t* __restrict__ W2t, const float* __restrict__ b2,
    const bf16_t* __restrict__ Ht,  const float* __restrict__ mub,
    const float* __restrict__ lvb,  bf16_t* __restrict__ zout)
{
    __shared__ bf16_t act[128 * 512];            // 128 KB
    __shared__ alignas(16) char wbuf[2 * 16384]; // 32 KB ping-pong
    const int t = threadIdx.x;
    const int wave = t >> 6, lane = t & 63, l31 = lane & 31, kg = lane >> 5;
    const int wm = wave >> 2, wn = wave & 3;
    const size_t r0 = (size_t)blockIdx.x * 128;

    // stage x tile (fp32 -> bf16, swizzled)
    for (int it = 0; it < 32; ++it) {
        int flat = it * 512 + t;
        int row = flat >> 7, c4 = flat & 127;
        float4 v = ((const float4*)(x + (r0 + row) * 512))[c4];
        bf16x4 h = { (bf16_t)v.x, (bf16_t)v.y, (bf16_t)v.z, (bf16_t)v.w };
        *(bf16x4*)((char*)act + act_off(row, c4 * 8)) = h;
    }
    asm volatile("s_waitcnt lgkmcnt(0)" ::: "memory");

    f32x16 acc[2][4];
    zero32(acc);
    layer_rs<32>(acc, act, wbuf, W1t, t, wave, lane, wm, wn, l31, kg);
    epi_lds32<true>(acc, b1, act, wm, wn, l31, kg);
    asm volatile("s_waitcnt lgkmcnt(0)" ::: "memory");
    __builtin_amdgcn_s_barrier();

    zero32(acc);
    layer_rs<32>(acc, act, wbuf, W2t, t, wave, lane, wm, wn, l31, kg);
    epi_lds32<true>(acc, b2, act, wm, wn, l31, kg);
    asm volatile("s_waitcnt lgkmcnt(0)" ::: "memory");
    __builtin_amdgcn_s_barrier();

    zero32(acc);
    layer_rs<32>(acc, act, wbuf, Ht, t, wave, lane, wm, wn, l31, kg);
    epi_lds32<false>(acc, (wn < 2) ? mub : (lvb - 256), act, wm, wn, l31, kg);
    asm volatile("s_waitcnt lgkmcnt(0)" ::: "memory");
    __builtin_amdgcn_s_barrier();

    // z = mu + eps * T^1.5 * exp(0.5*lv); mu cols 0-255, lv cols 256-511
    const int ce = (t & 63) * 4;
    const int ag = ce >> 6;
    const float tp = (ag == 0) ? 1.8371173070873836f
                   : (ag == 1) ? 0.35355339059327373f
                   : (ag == 2) ? 1.0f
                               : 0.7155417527999327f;
    const int rb = t >> 6;
    for (int it = 0; it < 16; ++it) {
        int row = it * 8 + rb;
        bf16x4 mu4 = *(const bf16x4*)((const char*)act + act_off(row, ce * 2));
        bf16x4 lv4 = *(const bf16x4*)((const char*)act + act_off(row, (ce + 256) * 2));
        float4 ep4 = *(const float4*)(eps + (r0 + row) * 256 + ce);
        bf16x4 zo;
        zo[0] = (bf16_t)fmaf(ep4.x * tp, expf(0.5f * (float)lv4[0]), (float)mu4[0]);
        zo[1] = (bf16_t)fmaf(ep4.y * tp, expf(0.5f * (float)lv4[1]), (float)mu4[1]);
        zo[2] = (bf16_t)fmaf(ep4.z * tp, expf(0.5f * (float)lv4[2]), (float)mu4[2]);
        zo[3] = (bf16_t)fmaf(ep4.w * tp, expf(0.5f * (float)lv4[3]), (float)mu4[3]);
        *(bf16x4*)(zout + (r0 + row) * 256 + ce) = zo;
    }
}

// ---------- kernel 3: attention over 4 agents + consensus (unchanged) ----------
__global__ __launch_bounds__(512) void attn_kernel(
    const bf16_t* __restrict__ z,
    const bf16_t* __restrict__ Wqkvb, const float* __restrict__ bqkv,
    const bf16_t* __restrict__ Wob,   const float* __restrict__ bo,
    const bf16_t* __restrict__ Wcb,   const float* __restrict__ bc,
    bf16_t* __restrict__ zcb)
{
    __shared__ bf16_t zt[256 * 64];    // z tile, later ctx tile   (rowB 128)
    __shared__ bf16_t qt[256 * 192];   // qkv tile, later z_att    (rowB 384/128)
    const int t = threadIdx.x;
    const size_t s0 = (size_t)blockIdx.x * 64;

    for (int it = 0; it < 4; ++it) {
        int ch = it * 512 + t;
        int r = ch >> 3, cc = ch & 7;
        bf16x8 v = *(const bf16x8*)(z + s0 * 256 + r * 64 + cc * 8);
        lds_write16B(zt, r, cc * 16, 128, v);
    }
    __syncthreads();
    const int wave = t >> 6, lane = t & 63, l15 = lane & 15, lhi = lane >> 4;
    const int rbase = wave * 32;

    for (int cc = 0; cc < 4; ++cc) {
        f32x4 acc[2][3] = {};
#pragma unroll
        for (int ks = 0; ks < 2; ++ks) {
            int k = ks * 32 + lhi * 8;
            bf16x8 a0 = lds_read8(zt, rbase + l15, k, 128);
            bf16x8 a1 = lds_read8(zt, rbase + 16 + l15, k, 128);
#pragma unroll
            for (int cf = 0; cf < 3; ++cf) {
                bf16x8 b = *(const bf16x8*)(Wqkvb + (cc * 48 + cf * 16 + l15) * 64 + k);
                acc[0][cf] = MFMA16(a0, b, acc[0][cf]);
                acc[1][cf] = MFMA16(a1, b, acc[1][cf]);
            }
        }
#pragma unroll
        for (int cf = 0; cf < 3; ++cf) {
            int col = cc * 48 + cf * 16 + l15;
            float bs = bqkv[col];
#pragma unroll
            for (int rf = 0; rf < 2; ++rf)
#pragma unroll
                for (int r = 0; r < 4; ++r)
                    lds_write1(qt, rbase + rf * 16 + lhi * 4 + r, col, 384, acc[rf][cf][r] + bs);
        }
    }
    __syncthreads();

    if (t < 256) {
        const int sl = t >> 2, head = t & 3;
        bf16x8 qv[4][2], kv[4][2], vv[4][2];
#pragma unroll
        for (int a2 = 0; a2 < 4; ++a2) {
            int r = sl * 4 + a2;
#pragma unroll
            for (int i = 0; i < 2; ++i) {
                qv[a2][i] = lds_read16B(qt, r, head * 32 + 16 * i, 384);
                kv[a2][i] = lds_read16B(qt, r, 128 + head * 32 + 16 * i, 384);
                vv[a2][i] = lds_read16B(qt, r, 256 + head * 32 + 16 * i, 384);
            }
        }
        float sc[4][4];
#pragma unroll
        for (int qa = 0; qa < 4; ++qa)
#pragma unroll
            for (int ka = 0; ka < 4; ++ka) {
                float s = 0.f;
#pragma unroll
                for (int i = 0; i < 2; ++i)
#pragma unroll
                    for (int j = 0; j < 8; ++j)
                        s += (float)qv[qa][i][j] * (float)kv[ka][i][j];
                sc[qa][ka] = s * 0.25f;
            }
#pragma unroll
        for (int qa = 0; qa < 4; ++qa) {
            float m = fmaxf(fmaxf(sc[qa][0], sc[qa][1]), fmaxf(sc[qa][2], sc[qa][3]));
            float e[4], sum = 0.f;
#pragma unroll
            for (int ka = 0; ka < 4; ++ka) { e[ka] = expf(sc[qa][ka] - m); sum += e[ka]; }
            float inv = 1.f / sum;
#pragma unroll
            for (int i = 0; i < 2; ++i) {
                bf16x8 cv;
#pragma unroll
                for (int j = 0; j < 8; ++j) {
                    float cval = 0.f;
#pragma unroll
                    for (int ka = 0; ka < 4; ++ka) cval += e[ka] * inv * (float)vv[ka][i][j];
                    cv[j] = (bf16_t)cval;
                }
                lds_write16B(zt, sl * 4 + qa, head * 32 + 16 * i, 128, cv);
            }
        }
    }
    __syncthreads();

    {   // z_att = ctx @ Wo^T + bo
        f32x4 acc[2][4] = {};
#pragma unroll
        for (int ks = 0; ks < 2; ++ks) {
            int k = ks * 32 + lhi * 8;
            bf16x8 a0 = lds_read8(zt, rbase + l15, k, 128);
            bf16x8 a1 = lds_read8(zt, rbase + 16 + l15, k, 128);
#pragma unroll
            for (int cf = 0; cf < 4; ++cf) {
                bf16x8 b = *(const bf16x8*)(Wob + (cf * 16 + l15) * 64 + k);
                acc[0][cf] = MFMA16(a0, b, acc[0][cf]);
                acc[1][cf] = MFMA16(a1, b, acc[1][cf]);
            }
        }
        __syncthreads();
#pragma unroll
        for (int cf = 0; cf < 4; ++cf) {
            int col = cf * 16 + l15;
            float bs = bo[col];
#pragma unroll
            for (int rf = 0; rf < 2; ++rf)
#pragma unroll
                for (int r = 0; r < 4; ++r)
                    lds_write1(qt, rbase + rf * 16 + lhi * 4 + r, col, 128, acc[rf][cf][r] + bs);
        }
    }
    __syncthreads();

    {   // z_consensus = z_att.reshape(64,256) @ Wc^T + bc
        f32x4 acc2[2] = {};
        const int rfw = wave >> 1, cbase = (wave & 1) * 2;
        const int srow = rfw * 16 + l15;
#pragma unroll
        for (int ks = 0; ks < 8; ++ks) {
            int k = ks * 32 + lhi * 8;
            int byte = (srow << 9) + (k << 1);
            byte ^= ((((srow << 2) + (k >> 6)) & 7) << 4);
            bf16x8 a = *(const bf16x8*)((const char*)qt + byte);
#pragma unroll
            for (int i = 0; i < 2; ++i) {
                bf16x8 b = *(const bf16x8*)(Wcb + ((cbase + i) * 16 + l15) * 256 + k);
                acc2[i] = MFMA16(a, b, acc2[i]);
            }
        }
#pragma unroll
        for (int i = 0; i < 2; ++i) {
            int col = (cbase + i) * 16 + l15;
            float bs = bc[col];
#pragma unroll
            for (int r = 0; r < 4; ++r) {
                int s = (int)(s0) + rfw * 16 + lhi * 4 + r;
                zcb[(size_t)s * 64 + col] = (bf16_t)(acc2[i][r] + bs);
            }
        }
    }
}

// ---------- kernel 4: fused 3-layer decoder (128-row, 160 KB, reg-staged pipe) ----------
__global__ __launch_bounds__(512, 2) void dec_kernel(
    const bf16_t* __restrict__ z, const bf16_t* __restrict__ zc,
    const bf16_t* __restrict__ Wd1t, const float* __restrict__ bd1,
    const bf16_t* __restrict__ Wd2t, const float* __restrict__ bd2,
    const bf16_t* __restrict__ Wd3t, const float* __restrict__ bd3,
    float* __restrict__ out)
{
    __shared__ bf16_t act[128 * 512];            // 128 KB (latents in cols 0..63)
    __shared__ alignas(16) char wbuf[2 * 16384]; // 32 KB ping-pong
    const int t = threadIdx.x;
    const int wave = t >> 6, lane = t & 63, l31 = lane & 31, kg = lane >> 5;
    const int wm = wave >> 2, wn = wave & 3;
    const long r0 = (long)blockIdx.x * 128;

    // gather latent rows into act cols 0..63: row = s*5 + j
    for (int it = 0; it < 2; ++it) {
        int flat = it * 512 + t;
        int row = flat >> 3, ch = flat & 7;
        long rg = r0 + row;
        int s5 = (int)(rg / 5), j = (int)(rg - (long)s5 * 5);
        const bf16_t* src = (j == 0) ? (zc + (size_t)s5 * 64)
                                     : (z + (size_t)s5 * 256 + (j - 1) * 64);
        bf16x8 v = *(const bf16x8*)(src + ch * 8);
        *(bf16x8*)((char*)act + act_off(row, ch * 16)) = v;
    }
    asm volatile("s_waitcnt lgkmcnt(0)" ::: "memory");

    f32x16 acc[2][4];
    zero32(acc);
    layer_rs<4>(acc, act, wbuf, Wd1t, t, wave, lane, wm, wn, l31, kg);
    epi_lds32<true>(acc, bd1, act, wm, wn, l31, kg);
    asm volatile("s_waitcnt lgkmcnt(0)" ::: "memory");
    __builtin_amdgcn_s_barrier();

    zero32(acc);
    layer_rs<32>(acc, act, wbuf, Wd2t, t, wave, lane, wm, wn, l31, kg);
    epi_lds32<true>(acc, bd2, act, wm, wn, l31, kg);
    asm volatile("s_waitcnt lgkmcnt(0)" ::: "memory");
    __builtin_amdgcn_s_barrier();

    zero32(acc);
    layer_rs<32>(acc, act, wbuf, Wd3t, t, wave, lane, wm, wn, l31, kg);
    epi_global32(acc, bd3, out, r0, wm, wn, l31, kg);
}

// ---------- launcher ----------
extern "C" void kernel_launch(void* const* d_in, const int* in_sizes, int n_in,
                              void* d_out, int out_size, void* d_ws, size_t ws_size,
                              hipStream_t stream) {
    const float* x    = (const float*)d_in[0];
    const float* eps  = (const float*)d_in[1];
    const float* W1   = (const float*)d_in[2];
    const float* b1   = (const float*)d_in[3];
    const float* W2   = (const float*)d_in[4];
    const float* b2   = (const float*)d_in[5];
    const float* muW  = (const float*)d_in[6];
    const float* mub  = (const float*)d_in[7];
    const float* lvW  = (const float*)d_in[8];
    const float* lvb  = (const float*)d_in[9];
    const float* Wqkv = (const float*)d_in[10];
    const float* bqkv = (const float*)d_in[11];
    const float* Wo   = (const float*)d_in[12];
    const float* bo   = (const float*)d_in[13];
    const float* Wc   = (const float*)d_in[14];
    const float* bc   = (const float*)d_in[15];
    const float* Wd1  = (const float*)d_in[16];
    const float* bd1  = (const float*)d_in[17];
    const float* Wd2  = (const float*)d_in[18];
    const float* bd2  = (const float*)d_in[19];
    const float* Wd3  = (const float*)d_in[20];
    const float* bd3  = (const float*)d_in[21];
    float* out = (float*)d_out;

    bf16_t* wsb  = (bf16_t*)d_ws;
    bf16_t* W1t  = wsb + 0;
    bf16_t* W2t  = wsb + 262144;
    bf16_t* Ht   = wsb + 524288;    // [muW ; lvW] retiled
    bf16_t* Wqkvb= wsb + 786432;
    bf16_t* Wob  = wsb + 798720;
    bf16_t* Wcb  = wsb + 802816;
    bf16_t* Wd1t = wsb + 819200;
    bf16_t* Wd2t = wsb + 851968;
    bf16_t* Wd3t = wsb + 1114112;
    bf16_t* zbuf = wsb + 1376256;   // (B,256) bf16
    bf16_t* zcb  = wsb + 9764864;   // (B,64)  bf16

    cast_kernel<<<dim3(5376), dim3(256), 0, stream>>>(
        W1, W2, muW, lvW, Wqkv, Wo, Wc, Wd1, Wd2, Wd3, wsb);
    enc_kernel<<<dim3(256), dim3(512), 0, stream>>>(
        x, eps, W1t, b1, W2t, b2, Ht, mub, lvb, zbuf);
    attn_kernel<<<dim3(512), dim3(512), 0, stream>>>(
        zbuf, Wqkvb, bqkv, Wob, bo, Wcb, bc, zcb);
    dec_kernel<<<dim3(1280), dim3(512), 0, stream>>>(
        zbuf, zcb, Wd1t, bd1, Wd2t, bd2, Wd3t, bd3, out);
}

// Round 17
// 382.837 us; speedup vs baseline: 1.4320x; 1.1859x over previous
//
#include <hip/hip_runtime.h>

typedef __bf16 bf16_t;
typedef __bf16 bf16x8 __attribute__((ext_vector_type(8)));
typedef __bf16 bf16x4 __attribute__((ext_vector_type(4)));
typedef float  f32x4  __attribute__((ext_vector_type(4)));
typedef float  f32x16 __attribute__((ext_vector_type(16)));

#define MFMA16(a,b,c) __builtin_amdgcn_mfma_f32_16x16x32_bf16((a),(b),(c),0,0,0)
#define MFMA32(a,b,c) __builtin_amdgcn_mfma_f32_32x32x16_bf16((a),(b),(c),0,0,0)
#define GLOBAL_AS __attribute__((address_space(1)))
#define LDS_AS    __attribute__((address_space(3)))
#define MEMFENCE  asm volatile("" ::: "memory")

// ---------- act LDS for dec: [128][512] bf16, XOR swizzle (row&15)<<4 ----------
__device__ __forceinline__ int act_off(int row, int kByte) {
    int byte = (row << 10) + kByte;
    return byte ^ ((row & 15) << 4);
}

// ---------- legacy swizzled helpers ((row&7)<<4) — enc R9 path + attn ----------
__device__ __forceinline__ bf16x8 lds_read8(const bf16_t* base, int row, int k, int rowB) {
    int byte = row * rowB + (k << 1);
    byte ^= ((row & 7) << 4);
    return *(const bf16x8*)((const char*)base + byte);
}
__device__ __forceinline__ void lds_write8B(bf16_t* base, int row, int col, int rowB, bf16x4 v) {
    int byte = row * rowB + (col << 1);
    byte ^= ((row & 7) << 4);
    *(bf16x4*)((char*)base + byte) = v;
}
__device__ __forceinline__ bf16x4 lds_read8B(const bf16_t* base, int row, int col, int rowB) {
    int byte = row * rowB + (col << 1);
    byte ^= ((row & 7) << 4);
    return *(const bf16x4*)((const char*)base + byte);
}
__device__ __forceinline__ void lds_write1(bf16_t* base, int row, int col, int rowB, float v) {
    int byte = row * rowB + (col << 1);
    byte ^= ((row & 7) << 4);
    *(bf16_t*)((char*)base + byte) = (bf16_t)v;
}
__device__ __forceinline__ void lds_write16B(bf16_t* base, int row, int colbyte, int rowB, bf16x8 v) {
    int byte = row * rowB + colbyte;
    byte ^= ((row & 7) << 4);
    *(bf16x8*)((char*)base + byte) = v;
}
__device__ __forceinline__ bf16x8 lds_read16B(const bf16_t* base, int row, int colbyte, int rowB) {
    int byte = row * rowB + colbyte;
    byte ^= ((row & 7) << 4);
    return *(const bf16x8*)((const char*)base + byte);
}

__device__ __forceinline__ void gload_lds16(const void* g, void* l) {
    __builtin_amdgcn_global_load_lds((const GLOBAL_AS void*)g, (LDS_AS void*)l, 16, 0, 0);
}

// =================== ENC engine (R9-verified): BK=32 tiles, 3 gload buffers ===================
// W tile 32KB: [kg(4)][col(512)][16B] -> element (col, k = tile*32 + kg*8 + e)
__device__ __forceinline__ void stageW32(const bf16_t* __restrict__ Wt, int tile,
                                         char* wbuf, int bufIdx, int wave, int lane) {
    const char* s = (const char*)Wt + (size_t)tile * 32768 + wave * 4096 + lane * 16;
    char* d = wbuf + bufIdx * 32768 + wave * 4096;
#pragma unroll
    for (int c = 0; c < 4; ++c)
        gload_lds16(s + c * 1024, d + c * 1024);
}

// per-wave tile 64x64, MFMA16 acc[4][4]: C[row=rf*16+l15][col=n0+cf*16+lhi*4+r]
template<int NS, bool CONT, int TB>
__device__ __forceinline__ void layer_gl(f32x4 (&acc)[4][4],
    const bf16_t* act, char* wbuf,
    const bf16_t* __restrict__ Wt, const bf16_t* __restrict__ Wn,
    int wave, int lane, int n0, int l15, int lhi)
{
#pragma unroll
    for (int s = 0; s < NS; ++s) {
        if (s == NS - 1 && !CONT) {
            asm volatile("s_waitcnt vmcnt(0)" ::: "memory");
        } else {
            asm volatile("s_waitcnt vmcnt(4)" ::: "memory");
        }
        __builtin_amdgcn_s_barrier();
        if (s + 2 < NS)  stageW32(Wt, s + 2,      wbuf, (TB + s + 2) % 3, wave, lane);
        else if (CONT)   stageW32(Wn, s + 2 - NS, wbuf, (TB + s + 2) % 3, wave, lane);
        const char* bb = wbuf + ((TB + s) % 3) * 32768 + lhi * 8192;
        bf16x8 a[4], b[4];
#pragma unroll
        for (int cf = 0; cf < 4; ++cf)
            b[cf] = *(const bf16x8*)(bb + (n0 + cf * 16 + l15) * 16);
#pragma unroll
        for (int rf = 0; rf < 4; ++rf)
            a[rf] = lds_read8(act, rf * 16 + l15, s * 32 + lhi * 8, 1024);
#pragma unroll
        for (int rf = 0; rf < 4; ++rf)
#pragma unroll
            for (int cf = 0; cf < 4; ++cf)
                acc[rf][cf] = MFMA16(b[cf], a[rf], acc[rf][cf]);
    }
}

__device__ __forceinline__ void zero4(f32x4 (&acc)[4][4]) {
#pragma unroll
    for (int rf = 0; rf < 4; ++rf)
#pragma unroll
        for (int cf = 0; cf < 4; ++cf)
            acc[rf][cf] = f32x4{0.f, 0.f, 0.f, 0.f};
}

template<bool RELU>
__device__ __forceinline__ void epi_lds16(const f32x4 (&acc)[4][4], const float* __restrict__ bias,
    bf16_t* dst, int n0, int l15, int lhi)
{
#pragma unroll
    for (int cf = 0; cf < 4; ++cf) {
        const int c0 = n0 + cf * 16 + lhi * 4;
        float4 b4 = *(const float4*)(bias + c0);
#pragma unroll
        for (int rf = 0; rf < 4; ++rf) {
            float v0 = acc[rf][cf][0] + b4.x;
            float v1 = acc[rf][cf][1] + b4.y;
            float v2 = acc[rf][cf][2] + b4.z;
            float v3 = acc[rf][cf][3] + b4.w;
            if (RELU) {
                v0 = fmaxf(v0, 0.f); v1 = fmaxf(v1, 0.f);
                v2 = fmaxf(v2, 0.f); v3 = fmaxf(v3, 0.f);
            }
            bf16x4 p = { (bf16_t)v0, (bf16_t)v1, (bf16_t)v2, (bf16_t)v3 };
            lds_write8B(dst, rf * 16 + l15, c0, 1024, p);
        }
    }
}

// =================== DEC engine (R16-verified): BK=16 reg-staged ping-pong ===================
// W tile 16KB: [kg(2)][col(512)][16B]
__device__ __forceinline__ void compute_step(f32x16 (&acc)[2][4],
    const bf16_t* act, const char* wbuf, int s, int wm, int wn, int l31, int kg)
{
    bf16x8 a[2], b[4];
#pragma unroll
    for (int cc = 0; cc < 4; ++cc)
        b[cc] = *(const bf16x8*)(wbuf + kg * 8192 + (wn * 128 + cc * 32 + l31) * 16);
#pragma unroll
    for (int rr = 0; rr < 2; ++rr)
        a[rr] = *(const bf16x8*)((const char*)act +
                    act_off(wm * 64 + rr * 32 + l31, s * 32 + kg * 16));
#pragma unroll
    for (int rr = 0; rr < 2; ++rr)
#pragma unroll
        for (int cc = 0; cc < 4; ++cc)
            acc[rr][cc] = MFMA32(b[cc], a[rr], acc[rr][cc]);
}

template<int NS>
__device__ __forceinline__ void layer_rs(f32x16 (&acc)[2][4],
    const bf16_t* act, char* wbuf, const bf16_t* __restrict__ Wt,
    int t, int wave, int lane, int wm, int wn, int l31, int kg)
{
    const char* gb = (const char*)Wt;
    {   // prologue: tile0 -> LDS direct; tile1 -> regs; wait for BOTH
        const char* s0 = gb + wave * 2048 + lane * 16;
        char* d0 = wbuf + wave * 2048;
        gload_lds16(s0, d0);
        gload_lds16(s0 + 1024, d0 + 1024);
    }
    MEMFENCE;
    uint4 rA0, rA1, rB0, rB1;
    rA0 = *(const uint4*)(gb + 16384 + t * 16);
    rA1 = *(const uint4*)(gb + 16384 + 8192 + t * 16);
    asm volatile("s_waitcnt vmcnt(0)" ::: "memory");
    __builtin_amdgcn_s_barrier();

#pragma unroll
    for (int p = 0; p < NS / 2; ++p) {
        {   // s = 2p, write pair = rA
            const int s = 2 * p;
            compute_step(acc, act, wbuf + (s & 1) * 16384, s, wm, wn, l31, kg);
            if (s + 2 < NS) {
                MEMFENCE;
                rB0 = *(const uint4*)(gb + (size_t)(s + 2) * 16384 + t * 16);
                rB1 = *(const uint4*)(gb + (size_t)(s + 2) * 16384 + 8192 + t * 16);
                MEMFENCE;
            }
            __builtin_amdgcn_s_barrier();
            if (s + 1 < NS) {
                if (s + 2 < NS) asm volatile("s_waitcnt vmcnt(2)" ::: "memory");
                else            asm volatile("s_waitcnt vmcnt(0)" ::: "memory");
                char* nb = wbuf + ((s + 1) & 1) * 16384;
                *(uint4*)(nb + t * 16) = rA0;
                *(uint4*)(nb + 8192 + t * 16) = rA1;
                asm volatile("s_waitcnt lgkmcnt(0)" ::: "memory");
            }
            __builtin_amdgcn_s_barrier();
        }
        {   // s = 2p+1, write pair = rB
            const int s = 2 * p + 1;
            compute_step(acc, act, wbuf + (s & 1) * 16384, s, wm, wn, l31, kg);
            if (s + 2 < NS) {
                MEMFENCE;
                rA0 = *(const uint4*)(gb + (size_t)(s + 2) * 16384 + t * 16);
                rA1 = *(const uint4*)(gb + (size_t)(s + 2) * 16384 + 8192 + t * 16);
                MEMFENCE;
            }
            __builtin_amdgcn_s_barrier();
            if (s + 1 < NS) {
                if (s + 2 < NS) asm volatile("s_waitcnt vmcnt(2)" ::: "memory");
                else            asm volatile("s_waitcnt vmcnt(0)" ::: "memory");
                char* nb = wbuf + ((s + 1) & 1) * 16384;
                *(uint4*)(nb + t * 16) = rB0;
                *(uint4*)(nb + 8192 + t * 16) = rB1;
                asm volatile("s_waitcnt lgkmcnt(0)" ::: "memory");
            }
            __builtin_amdgcn_s_barrier();
        }
    }
}

__device__ __forceinline__ void zero32(f32x16 (&acc)[2][4]) {
#pragma unroll
    for (int rr = 0; rr < 2; ++rr)
#pragma unroll
        for (int cc = 0; cc < 4; ++cc)
#pragma unroll
            for (int i = 0; i < 16; ++i) acc[rr][cc][i] = 0.f;
}

template<bool RELU>
__device__ __forceinline__ void epi_lds32(const f32x16 (&acc)[2][4], const float* __restrict__ bias,
    bf16_t* act, int wm, int wn, int l31, int kg)
{
#pragma unroll
    for (int cc = 0; cc < 4; ++cc)
#pragma unroll
    for (int q = 0; q < 4; ++q) {
        const int c0 = wn * 128 + cc * 32 + q * 8 + kg * 4;
        float4 b4 = *(const float4*)(bias + c0);
#pragma unroll
        for (int rr = 0; rr < 2; ++rr) {
            float v0 = acc[rr][cc][q * 4 + 0] + b4.x;
            float v1 = acc[rr][cc][q * 4 + 1] + b4.y;
            float v2 = acc[rr][cc][q * 4 + 2] + b4.z;
            float v3 = acc[rr][cc][q * 4 + 3] + b4.w;
            if (RELU) {
                v0 = fmaxf(v0, 0.f); v1 = fmaxf(v1, 0.f);
                v2 = fmaxf(v2, 0.f); v3 = fmaxf(v3, 0.f);
            }
            bf16x4 p = { (bf16_t)v0, (bf16_t)v1, (bf16_t)v2, (bf16_t)v3 };
            *(bf16x4*)((char*)act + act_off(wm * 64 + rr * 32 + l31, c0 * 2)) = p;
        }
    }
}
__device__ __forceinline__ void epi_global32(const f32x16 (&acc)[2][4], const float* __restrict__ bias,
    float* __restrict__ out, long r0, int wm, int wn, int l31, int kg)
{
#pragma unroll
    for (int cc = 0; cc < 4; ++cc)
#pragma unroll
    for (int q = 0; q < 4; ++q) {
        const int c0 = wn * 128 + cc * 32 + q * 8 + kg * 4;
        float4 b4 = *(const float4*)(bias + c0);
#pragma unroll
        for (int rr = 0; rr < 2; ++rr) {
            float4 o = { acc[rr][cc][q * 4 + 0] + b4.x, acc[rr][cc][q * 4 + 1] + b4.y,
                         acc[rr][cc][q * 4 + 2] + b4.z, acc[rr][cc][q * 4 + 3] + b4.w };
            *(float4*)(out + (r0 + wm * 64 + rr * 32 + l31) * 512 + c0) = o;
        }
    }
}

// ---------- kernel 1: cast + retile weights (enc: BK=32 layout, dec: BK=16 layout) ----------
__device__ __forceinline__ void decode32(int m, int& n, int& k) {   // [tile32k][kg4][col][8]
    int s = m >> 14, r = m & 16383;
    int kg = r >> 12, q = r & 4095;
    n = q >> 3;
    k = (s << 5) + (kg << 3) + (q & 7);
}
__device__ __forceinline__ void decode16(int m, int& n, int& k) {   // [tile8k][kg2][col][8]
    int s = m >> 13, r = m & 8191;
    int kg = r >> 12, q = r & 4095;
    n = q >> 3;
    k = (s << 4) + (kg << 3) + (q & 7);
}
__global__ __launch_bounds__(256) void cast_kernel(
    const float* __restrict__ W1, const float* __restrict__ W2,
    const float* __restrict__ muW, const float* __restrict__ lvW,
    const float* __restrict__ Wqkv, const float* __restrict__ Wo,
    const float* __restrict__ Wc, const float* __restrict__ Wd1,
    const float* __restrict__ Wd2, const float* __restrict__ Wd3,
    bf16_t* __restrict__ dst)
{
    int i = blockIdx.x * 256 + threadIdx.x;   // grid exactly covers 1376256
    float val;
    int n, k;
    if (i < 262144) {
        decode32(i, n, k);                    val = W1[n * 512 + k];
    } else if (i < 524288) {
        decode32(i - 262144, n, k);           val = W2[n * 512 + k];
    } else if (i < 786432) {
        decode32(i - 524288, n, k);
        val = (n < 256) ? muW[n * 512 + k] : lvW[(n - 256) * 512 + k];
    } else if (i < 798720) { val = Wqkv[i - 786432]; }
    else if (i < 802816)   { val = Wo[i - 798720]; }
    else if (i < 819200)   { val = Wc[i - 802816]; }
    else if (i < 851968) {
        decode16(i - 819200, n, k);           val = Wd1[n * 64 + k];
    } else if (i < 1114112) {
        decode16(i - 851968, n, k);           val = Wd2[n * 512 + k];
    } else {
        decode16(i - 1114112, n, k);          val = Wd3[n * 512 + k];
    }
    dst[i] = (bf16_t)val;
}

// ---------- kernel 2: encoder + heads + reparameterize (R9-verified structure) ----------
__global__ __launch_bounds__(512, 2) void enc_kernel(
    const float* __restrict__ x, const float* __restrict__ eps,
    const bf16_t* __restrict__ W1t, const float* __restrict__ b1,
    const bf16_t* __restrict__ W2t, const float* __restrict__ b2,
    const bf16_t* __restrict__ Ht,  const float* __restrict__ mub,
    const float* __restrict__ lvb,  bf16_t* __restrict__ zout)
{
    __shared__ bf16_t act[64 * 512];            // 64 KB
    __shared__ alignas(16) char wbuf[3 * 32768];// 96 KB
    const int t = threadIdx.x;
    const int wave = t >> 6, lane = t & 63, l15 = lane & 15, lhi = lane >> 4;
    const int n0 = wave * 64;
    const size_t r0 = (size_t)blockIdx.x * 64;

    stageW32(W1t, 0, wbuf, 0, wave, lane);
    stageW32(W1t, 1, wbuf, 1, wave, lane);

    // stage x tile (fp32 -> bf16, swizzled (row&7))
    for (int it = 0; it < 16; ++it) {
        int flat = it * 512 + t;
        int row = flat >> 7, c4 = flat & 127;
        float4 v = ((const float4*)(x + (r0 + row) * 512))[c4];
        bf16x4 h = { (bf16_t)v.x, (bf16_t)v.y, (bf16_t)v.z, (bf16_t)v.w };
        int byte = (row << 10) + (c4 << 3);
        byte ^= ((row & 7) << 4);
        *(bf16x4*)((char*)act + byte) = h;
    }
    asm volatile("s_waitcnt lgkmcnt(0)" ::: "memory");

    f32x4 acc[4][4];
    zero4(acc);
    layer_gl<16, true, 0>(acc, act, wbuf, W1t, W2t, wave, lane, n0, l15, lhi);
    __builtin_amdgcn_s_barrier();
    epi_lds16<true>(acc, b1, act, n0, l15, lhi);
    asm volatile("s_waitcnt lgkmcnt(0)" ::: "memory");
    __builtin_amdgcn_s_barrier();

    zero4(acc);
    layer_gl<16, true, 1>(acc, act, wbuf, W2t, Ht, wave, lane, n0, l15, lhi);
    __builtin_amdgcn_s_barrier();
    epi_lds16<true>(acc, b2, act, n0, l15, lhi);
    asm volatile("s_waitcnt lgkmcnt(0)" ::: "memory");
    __builtin_amdgcn_s_barrier();

    zero4(acc);
    layer_gl<16, false, 2>(acc, act, wbuf, Ht, (const bf16_t*)nullptr, wave, lane, n0, l15, lhi);
    __builtin_amdgcn_s_barrier();
    epi_lds16<false>(acc, (n0 < 256) ? (mub + 0) : (lvb - 256), act, n0, l15, lhi);
    asm volatile("s_waitcnt lgkmcnt(0)" ::: "memory");
    __builtin_amdgcn_s_barrier();

    // z = mu + eps * T^1.5 * exp(0.5*lv); mu cols 0-255, lv cols 256-511
    const int cc = (t & 63) * 4;
    const int ag = cc >> 6;
    const float tp = (ag == 0) ? 1.8371173070873836f
                   : (ag == 1) ? 0.35355339059327373f
                   : (ag == 2) ? 1.0f
                               : 0.7155417527999327f;
    const int rb = t >> 6;
    for (int it = 0; it < 8; ++it) {
        int row = it * 8 + rb;
        bf16x4 mu4 = lds_read8B(act, row, cc, 1024);
        bf16x4 lv4 = lds_read8B(act, row, cc + 256, 1024);
        float4 ep4 = *(const float4*)(eps + (r0 + row) * 256 + cc);
        bf16x4 zo;
        zo[0] = (bf16_t)fmaf(ep4.x * tp, expf(0.5f * (float)lv4[0]), (float)mu4[0]);
        zo[1] = (bf16_t)fmaf(ep4.y * tp, expf(0.5f * (float)lv4[1]), (float)mu4[1]);
        zo[2] = (bf16_t)fmaf(ep4.z * tp, expf(0.5f * (float)lv4[2]), (float)mu4[2]);
        zo[3] = (bf16_t)fmaf(ep4.w * tp, expf(0.5f * (float)lv4[3]), (float)mu4[3]);
        *(bf16x4*)(zout + (r0 + row) * 256 + cc) = zo;
    }
}

// ---------- kernel 3: attention over 4 agents + consensus (unchanged) ----------
__global__ __launch_bounds__(512) void attn_kernel(
    const bf16_t* __restrict__ z,
    const bf16_t* __restrict__ Wqkvb, const float* __restrict__ bqkv,
    const bf16_t* __restrict__ Wob,   const float* __restrict__ bo,
    const bf16_t* __restrict__ Wcb,   const float* __restrict__ bc,
    bf16_t* __restrict__ zcb)
{
    __shared__ bf16_t zt[256 * 64];    // z tile, later ctx tile   (rowB 128)
    __shared__ bf16_t qt[256 * 192];   // qkv tile, later z_att    (rowB 384/128)
    const int t = threadIdx.x;
    const size_t s0 = (size_t)blockIdx.x * 64;

    for (int it = 0; it < 4; ++it) {
        int ch = it * 512 + t;
        int r = ch >> 3, cc = ch & 7;
        bf16x8 v = *(const bf16x8*)(z + s0 * 256 + r * 64 + cc * 8);
        lds_write16B(zt, r, cc * 16, 128, v);
    }
    __syncthreads();
    const int wave = t >> 6, lane = t & 63, l15 = lane & 15, lhi = lane >> 4;
    const int rbase = wave * 32;

    for (int cc = 0; cc < 4; ++cc) {
        f32x4 acc[2][3] = {};
#pragma unroll
        for (int ks = 0; ks < 2; ++ks) {
            int k = ks * 32 + lhi * 8;
            bf16x8 a0 = lds_read8(zt, rbase + l15, k, 128);
            bf16x8 a1 = lds_read8(zt, rbase + 16 + l15, k, 128);
#pragma unroll
            for (int cf = 0; cf < 3; ++cf) {
                bf16x8 b = *(const bf16x8*)(Wqkvb + (cc * 48 + cf * 16 + l15) * 64 + k);
                acc[0][cf] = MFMA16(a0, b, acc[0][cf]);
                acc[1][cf] = MFMA16(a1, b, acc[1][cf]);
            }
        }
#pragma unroll
        for (int cf = 0; cf < 3; ++cf) {
            int col = cc * 48 + cf * 16 + l15;
            float bs = bqkv[col];
#pragma unroll
            for (int rf = 0; rf < 2; ++rf)
#pragma unroll
                for (int r = 0; r < 4; ++r)
                    lds_write1(qt, rbase + rf * 16 + lhi * 4 + r, col, 384, acc[rf][cf][r] + bs);
        }
    }
    __syncthreads();

    if (t < 256) {
        const int sl = t >> 2, head = t & 3;
        bf16x8 qv[4][2], kv[4][2], vv[4][2];
#pragma unroll
        for (int a2 = 0; a2 < 4; ++a2) {
            int r = sl * 4 + a2;
#pragma unroll
            for (int i = 0; i < 2; ++i) {
                qv[a2][i] = lds_read16B(qt, r, head * 32 + 16 * i, 384);
                kv[a2][i] = lds_read16B(qt, r, 128 + head * 32 + 16 * i, 384);
                vv[a2][i] = lds_read16B(qt, r, 256 + head * 32 + 16 * i, 384);
            }
        }
        float sc[4][4];
#pragma unroll
        for (int qa = 0; qa < 4; ++qa)
#pragma unroll
            for (int ka = 0; ka < 4; ++ka) {
                float s = 0.f;
#pragma unroll
                for (int i = 0; i < 2; ++i)
#pragma unroll
                    for (int j = 0; j < 8; ++j)
                        s += (float)qv[qa][i][j] * (float)kv[ka][i][j];
                sc[qa][ka] = s * 0.25f;
            }
#pragma unroll
        for (int qa = 0; qa < 4; ++qa) {
            float m = fmaxf(fmaxf(sc[qa][0], sc[qa][1]), fmaxf(sc[qa][2], sc[qa][3]));
            float e[4], sum = 0.f;
#pragma unroll
            for (int ka = 0; ka < 4; ++ka) { e[ka] = expf(sc[qa][ka] - m); sum += e[ka]; }
            float inv = 1.f / sum;
#pragma unroll
            for (int i = 0; i < 2; ++i) {
                bf16x8 cv;
#pragma unroll
                for (int j = 0; j < 8; ++j) {
                    float cval = 0.f;
#pragma unroll
                    for (int ka = 0; ka < 4; ++ka) cval += e[ka] * inv * (float)vv[ka][i][j];
                    cv[j] = (bf16_t)cval;
                }
                lds_write16B(zt, sl * 4 + qa, head * 32 + 16 * i, 128, cv);
            }
        }
    }
    __syncthreads();

    {   // z_att = ctx @ Wo^T + bo
        f32x4 acc[2][4] = {};
#pragma unroll
        for (int ks = 0; ks < 2; ++ks) {
            int k = ks * 32 + lhi * 8;
            bf16x8 a0 = lds_read8(zt, rbase + l15, k, 128);
            bf16x8 a1 = lds_read8(zt, rbase + 16 + l15, k, 128);
#pragma unroll
            for (int cf = 0; cf < 4; ++cf) {
                bf16x8 b = *(const bf16x8*)(Wob + (cf * 16 + l15) * 64 + k);
                acc[0][cf] = MFMA16(a0, b, acc[0][cf]);
                acc[1][cf] = MFMA16(a1, b, acc[1][cf]);
            }
        }
        __syncthreads();
#pragma unroll
        for (int cf = 0; cf < 4; ++cf) {
            int col = cf * 16 + l15;
            float bs = bo[col];
#pragma unroll
            for (int rf = 0; rf < 2; ++rf)
#pragma unroll
                for (int r = 0; r < 4; ++r)
                    lds_write1(qt, rbase + rf * 16 + lhi * 4 + r, col, 128, acc[rf][cf][r] + bs);
        }
    }
    __syncthreads();

    {   // z_consensus = z_att.reshape(64,256) @ Wc^T + bc
        f32x4 acc2[2] = {};
        const int rfw = wave >> 1, cbase = (wave & 1) * 2;
        const int srow = rfw * 16 + l15;
#pragma unroll
        for (int ks = 0; ks < 8; ++ks) {
            int k = ks * 32 + lhi * 8;
            int byte = (srow << 9) + (k << 1);
            byte ^= ((((srow << 2) + (k >> 6)) & 7) << 4);
            bf16x8 a = *(const bf16x8*)((const char*)qt + byte);
#pragma unroll
            for (int i = 0; i < 2; ++i) {
                bf16x8 b = *(const bf16x8*)(Wcb + ((cbase + i) * 16 + l15) * 256 + k);
                acc2[i] = MFMA16(a, b, acc2[i]);
            }
        }
#pragma unroll
        for (int i = 0; i < 2; ++i) {
            int col = (cbase + i) * 16 + l15;
            float bs = bc[col];
#pragma unroll
            for (int r = 0; r < 4; ++r) {
                int s = (int)(s0) + rfw * 16 + lhi * 4 + r;
                zcb[(size_t)s * 64 + col] = (bf16_t)(acc2[i][r] + bs);
            }
        }
    }
}

// ---------- kernel 4: fused 3-layer decoder (R16-verified: 128-row reg-staged) ----------
__global__ __launch_bounds__(512, 2) void dec_kernel(
    const bf16_t* __restrict__ z, const bf16_t* __restrict__ zc,
    const bf16_t* __restrict__ Wd1t, const float* __restrict__ bd1,
    const bf16_t* __restrict__ Wd2t, const float* __restrict__ bd2,
    const bf16_t* __restrict__ Wd3t, const float* __restrict__ bd3,
    float* __restrict__ out)
{
    __shared__ bf16_t act[128 * 512];            // 128 KB (latents in cols 0..63)
    __shared__ alignas(16) char wbuf[2 * 16384]; // 32 KB ping-pong
    const int t = threadIdx.x;
    const int wave = t >> 6, lane = t & 63, l31 = lane & 31, kg = lane >> 5;
    const int wm = wave >> 2, wn = wave & 3;
    const long r0 = (long)blockIdx.x * 128;

    // gather latent rows into act cols 0..63: row = s*5 + j
    for (int it = 0; it < 2; ++it) {
        int flat = it * 512 + t;
        int row = flat >> 3, ch = flat & 7;
        long rg = r0 + row;
        int s5 = (int)(rg / 5), j = (int)(rg - (long)s5 * 5);
        const bf16_t* src = (j == 0) ? (zc + (size_t)s5 * 64)
                                     : (z + (size_t)s5 * 256 + (j - 1) * 64);
        bf16x8 v = *(const bf16x8*)(src + ch * 8);
        *(bf16x8*)((char*)act + act_off(row, ch * 16)) = v;
    }
    asm volatile("s_waitcnt lgkmcnt(0)" ::: "memory");

    f32x16 acc[2][4];
    zero32(acc);
    layer_rs<4>(acc, act, wbuf, Wd1t, t, wave, lane, wm, wn, l31, kg);
    epi_lds32<true>(acc, bd1, act, wm, wn, l31, kg);
    asm volatile("s_waitcnt lgkmcnt(0)" ::: "memory");
    __builtin_amdgcn_s_barrier();

    zero32(acc);
    layer_rs<32>(acc, act, wbuf, Wd2t, t, wave, lane, wm, wn, l31, kg);
    epi_lds32<true>(acc, bd2, act, wm, wn, l31, kg);
    asm volatile("s_waitcnt lgkmcnt(0)" ::: "memory");
    __builtin_amdgcn_s_barrier();

    zero32(acc);
    layer_rs<32>(acc, act, wbuf, Wd3t, t, wave, lane, wm, wn, l31, kg);
    epi_global32(acc, bd3, out, r0, wm, wn, l31, kg);
}

// ---------- launcher ----------
extern "C" void kernel_launch(void* const* d_in, const int* in_sizes, int n_in,
                              void* d_out, int out_size, void* d_ws, size_t ws_size,
                              hipStream_t stream) {
    const float* x    = (const float*)d_in[0];
    const float* eps  = (const float*)d_in[1];
    const float* W1   = (const float*)d_in[2];
    const float* b1   = (const float*)d_in[3];
    const float* W2   = (const float*)d_in[4];
    const float* b2   = (const float*)d_in[5];
    const float* muW  = (const float*)d_in[6];
    const float* mub  = (const float*)d_in[7];
    const float* lvW  = (const float*)d_in[8];
    const float* lvb  = (const float*)d_in[9];
    const float* Wqkv = (const float*)d_in[10];
    const float* bqkv = (const float*)d_in[11];
    const float* Wo   = (const float*)d_in[12];
    const float* bo   = (const float*)d_in[13];
    const float* Wc   = (const float*)d_in[14];
    const float* bc   = (const float*)d_in[15];
    const float* Wd1  = (const float*)d_in[16];
    const float* bd1  = (const float*)d_in[17];
    const float* Wd2  = (const float*)d_in[18];
    const float* bd2  = (const float*)d_in[19];
    const float* Wd3  = (const float*)d_in[20];
    const float* bd3  = (const float*)d_in[21];
    float* out = (float*)d_out;

    bf16_t* wsb  = (bf16_t*)d_ws;
    bf16_t* W1t  = wsb + 0;
    bf16_t* W2t  = wsb + 262144;
    bf16_t* Ht   = wsb + 524288;    // [muW ; lvW] retiled (BK=32)
    bf16_t* Wqkvb= wsb + 786432;
    bf16_t* Wob  = wsb + 798720;
    bf16_t* Wcb  = wsb + 802816;
    bf16_t* Wd1t = wsb + 819200;    // BK=16
    bf16_t* Wd2t = wsb + 851968;
    bf16_t* Wd3t = wsb + 1114112;
    bf16_t* zbuf = wsb + 1376256;   // (B,256) bf16
    bf16_t* zcb  = wsb + 9764864;   // (B,64)  bf16

    cast_kernel<<<dim3(5376), dim3(256), 0, stream>>>(
        W1, W2, muW, lvW, Wqkv, Wo, Wc, Wd1, Wd2, Wd3, wsb);
    enc_kernel<<<dim3(512), dim3(512), 0, stream>>>(
        x, eps, W1t, b1, W2t, b2, Ht, mub, lvb, zbuf);
    attn_kernel<<<dim3(512), dim3(512), 0, stream>>>(
        zbuf, Wqkvb, bqkv, Wob, bo, Wcb, bc, zcb);
    dec_kernel<<<dim3(1280), dim3(512), 0, stream>>>(
        zbuf, zcb, Wd1t, bd1, Wd2t, bd2, Wd3t, bd3, out);
}

// Round 18
// 380.770 us; speedup vs baseline: 1.4398x; 1.0054x over previous
//
#include <hip/hip_runtime.h>

typedef __bf16 bf16_t;
typedef __bf16 bf16x8 __attribute__((ext_vector_type(8)));
typedef __bf16 bf16x4 __attribute__((ext_vector_type(4)));
typedef float  f32x4  __attribute__((ext_vector_type(4)));
typedef float  f32x16 __attribute__((ext_vector_type(16)));

#define MFMA16(a,b,c) __builtin_amdgcn_mfma_f32_16x16x32_bf16((a),(b),(c),0,0,0)
#define MFMA32(a,b,c) __builtin_amdgcn_mfma_f32_32x32x16_bf16((a),(b),(c),0,0,0)
#define GLOBAL_AS __attribute__((address_space(1)))
#define LDS_AS    __attribute__((address_space(3)))
#define MEMFENCE  asm volatile("" ::: "memory")

// ---------- act LDS for dec: [128][512] bf16, XOR swizzle (row&15)<<4 ----------
__device__ __forceinline__ int act_off(int row, int kByte) {
    int byte = (row << 10) + kByte;
    return byte ^ ((row & 15) << 4);
}

// ---------- legacy swizzled helpers ((row&7)<<4) — enc R9 path + attn ----------
__device__ __forceinline__ bf16x8 lds_read8(const bf16_t* base, int row, int k, int rowB) {
    int byte = row * rowB + (k << 1);
    byte ^= ((row & 7) << 4);
    return *(const bf16x8*)((const char*)base + byte);
}
__device__ __forceinline__ void lds_write8B(bf16_t* base, int row, int col, int rowB, bf16x4 v) {
    int byte = row * rowB + (col << 1);
    byte ^= ((row & 7) << 4);
    *(bf16x4*)((char*)base + byte) = v;
}
__device__ __forceinline__ bf16x4 lds_read8B(const bf16_t* base, int row, int col, int rowB) {
    int byte = row * rowB + (col << 1);
    byte ^= ((row & 7) << 4);
    return *(const bf16x4*)((const char*)base + byte);
}
__device__ __forceinline__ void lds_write1(bf16_t* base, int row, int col, int rowB, float v) {
    int byte = row * rowB + (col << 1);
    byte ^= ((row & 7) << 4);
    *(bf16_t*)((char*)base + byte) = (bf16_t)v;
}
__device__ __forceinline__ void lds_write16B(bf16_t* base, int row, int colbyte, int rowB, bf16x8 v) {
    int byte = row * rowB + colbyte;
    byte ^= ((row & 7) << 4);
    *(bf16x8*)((char*)base + byte) = v;
}
__device__ __forceinline__ bf16x8 lds_read16B(const bf16_t* base, int row, int colbyte, int rowB) {
    int byte = row * rowB + colbyte;
    byte ^= ((row & 7) << 4);
    return *(const bf16x8*)((const char*)base + byte);
}

__device__ __forceinline__ void gload_lds16(const void* g, void* l) {
    __builtin_amdgcn_global_load_lds((const GLOBAL_AS void*)g, (LDS_AS void*)l, 16, 0, 0);
}

// =================== ENC engine (R9-verified): BK=32 tiles, 3 gload buffers ===================
// W tile 32KB: [kg(4)][col(512)][16B] -> element (col, k = tile*32 + kg*8 + e)
__device__ __forceinline__ void stageW32(const bf16_t* __restrict__ Wt, int tile,
                                         char* wbuf, int bufIdx, int wave, int lane) {
    const char* s = (const char*)Wt + (size_t)tile * 32768 + wave * 4096 + lane * 16;
    char* d = wbuf + bufIdx * 32768 + wave * 4096;
#pragma unroll
    for (int c = 0; c < 4; ++c)
        gload_lds16(s + c * 1024, d + c * 1024);
}

// per-wave tile 64x64, MFMA16 acc[4][4]: C[row=rf*16+l15][col=n0+cf*16+lhi*4+r]
template<int NS, bool CONT, int TB>
__device__ __forceinline__ void layer_gl(f32x4 (&acc)[4][4],
    const bf16_t* act, char* wbuf,
    const bf16_t* __restrict__ Wt, const bf16_t* __restrict__ Wn,
    int wave, int lane, int n0, int l15, int lhi)
{
#pragma unroll
    for (int s = 0; s < NS; ++s) {
        if (s == NS - 1 && !CONT) {
            asm volatile("s_waitcnt vmcnt(0)" ::: "memory");
        } else {
            asm volatile("s_waitcnt vmcnt(4)" ::: "memory");
        }
        __builtin_amdgcn_s_barrier();
        if (s + 2 < NS)  stageW32(Wt, s + 2,      wbuf, (TB + s + 2) % 3, wave, lane);
        else if (CONT)   stageW32(Wn, s + 2 - NS, wbuf, (TB + s + 2) % 3, wave, lane);
        const char* bb = wbuf + ((TB + s) % 3) * 32768 + lhi * 8192;
        bf16x8 a[4], b[4];
#pragma unroll
        for (int cf = 0; cf < 4; ++cf)
            b[cf] = *(const bf16x8*)(bb + (n0 + cf * 16 + l15) * 16);
#pragma unroll
        for (int rf = 0; rf < 4; ++rf)
            a[rf] = lds_read8(act, rf * 16 + l15, s * 32 + lhi * 8, 1024);
#pragma unroll
        for (int rf = 0; rf < 4; ++rf)
#pragma unroll
            for (int cf = 0; cf < 4; ++cf)
                acc[rf][cf] = MFMA16(b[cf], a[rf], acc[rf][cf]);
    }
}

__device__ __forceinline__ void zero4(f32x4 (&acc)[4][4]) {
#pragma unroll
    for (int rf = 0; rf < 4; ++rf)
#pragma unroll
        for (int cf = 0; cf < 4; ++cf)
            acc[rf][cf] = f32x4{0.f, 0.f, 0.f, 0.f};
}

template<bool RELU>
__device__ __forceinline__ void epi_lds16(const f32x4 (&acc)[4][4], const float* __restrict__ bias,
    bf16_t* dst, int n0, int l15, int lhi)
{
#pragma unroll
    for (int cf = 0; cf < 4; ++cf) {
        const int c0 = n0 + cf * 16 + lhi * 4;
        float4 b4 = *(const float4*)(bias + c0);
#pragma unroll
        for (int rf = 0; rf < 4; ++rf) {
            float v0 = acc[rf][cf][0] + b4.x;
            float v1 = acc[rf][cf][1] + b4.y;
            float v2 = acc[rf][cf][2] + b4.z;
            float v3 = acc[rf][cf][3] + b4.w;
            if (RELU) {
                v0 = fmaxf(v0, 0.f); v1 = fmaxf(v1, 0.f);
                v2 = fmaxf(v2, 0.f); v3 = fmaxf(v3, 0.f);
            }
            bf16x4 p = { (bf16_t)v0, (bf16_t)v1, (bf16_t)v2, (bf16_t)v3 };
            lds_write8B(dst, rf * 16 + l15, c0, 1024, p);
        }
    }
}

// =================== DEC engine: BK=16 reg-staged ping-pong, 1 barrier/step ===================
// W tile 16KB: [kg(2)][col(512)][16B]
__device__ __forceinline__ void compute_step(f32x16 (&acc)[2][4],
    const bf16_t* act, const char* wbuf, int s, int wm, int wn, int l31, int kg)
{
    bf16x8 a[2], b[4];
#pragma unroll
    for (int cc = 0; cc < 4; ++cc)
        b[cc] = *(const bf16x8*)(wbuf + kg * 8192 + (wn * 128 + cc * 32 + l31) * 16);
#pragma unroll
    for (int rr = 0; rr < 2; ++rr)
        a[rr] = *(const bf16x8*)((const char*)act +
                    act_off(wm * 64 + rr * 32 + l31, s * 32 + kg * 16));
#pragma unroll
    for (int rr = 0; rr < 2; ++rr)
#pragma unroll
        for (int cc = 0; cc < 4; ++cc)
            acc[rr][cc] = MFMA32(b[cc], a[rr], acc[rr][cc]);
}

// Sync proof (ping-pong): write of tile s+1 -> buf[(s+1)&1]; last readers of that
// buffer were compute(s-1), and all waves passed the end-of-step barrier of s-1
// before entering step s. So no barrier needed between compute(s) and the write.
// One barrier/step (after lgkmcnt(0)) publishes tile s+1 for compute(s+1).
template<int NS>
__device__ __forceinline__ void layer_rs(f32x16 (&acc)[2][4],
    const bf16_t* act, char* wbuf, const bf16_t* __restrict__ Wt,
    int t, int wave, int lane, int wm, int wn, int l31, int kg)
{
    const char* gb = (const char*)Wt;
    {   // prologue: tile0 -> LDS direct; tile1 -> regs; wait for BOTH
        const char* s0 = gb + wave * 2048 + lane * 16;
        char* d0 = wbuf + wave * 2048;
        gload_lds16(s0, d0);
        gload_lds16(s0 + 1024, d0 + 1024);
    }
    MEMFENCE;
    uint4 rA0, rA1, rB0, rB1;
    rA0 = *(const uint4*)(gb + 16384 + t * 16);
    rA1 = *(const uint4*)(gb + 16384 + 8192 + t * 16);
    asm volatile("s_waitcnt vmcnt(0)" ::: "memory");
    __builtin_amdgcn_s_barrier();

#pragma unroll
    for (int p = 0; p < NS / 2; ++p) {
        {   // s = 2p, write pair = rA
            const int s = 2 * p;
            compute_step(acc, act, wbuf + (s & 1) * 16384, s, wm, wn, l31, kg);
            if (s + 2 < NS) {
                MEMFENCE;
                rB0 = *(const uint4*)(gb + (size_t)(s + 2) * 16384 + t * 16);
                rB1 = *(const uint4*)(gb + (size_t)(s + 2) * 16384 + 8192 + t * 16);
                MEMFENCE;
            }
            if (s + 1 < NS) {
                if (s + 2 < NS) asm volatile("s_waitcnt vmcnt(2)" ::: "memory");
                else            asm volatile("s_waitcnt vmcnt(0)" ::: "memory");
                char* nb = wbuf + ((s + 1) & 1) * 16384;
                *(uint4*)(nb + t * 16) = rA0;
                *(uint4*)(nb + 8192 + t * 16) = rA1;
                asm volatile("s_waitcnt lgkmcnt(0)" ::: "memory");
            }
            __builtin_amdgcn_s_barrier();
        }
        {   // s = 2p+1, write pair = rB
            const int s = 2 * p + 1;
            compute_step(acc, act, wbuf + (s & 1) * 16384, s, wm, wn, l31, kg);
            if (s + 2 < NS) {
                MEMFENCE;
                rA0 = *(const uint4*)(gb + (size_t)(s + 2) * 16384 + t * 16);
                rA1 = *(const uint4*)(gb + (size_t)(s + 2) * 16384 + 8192 + t * 16);
                MEMFENCE;
            }
            if (s + 1 < NS) {
                if (s + 2 < NS) asm volatile("s_waitcnt vmcnt(2)" ::: "memory");
                else            asm volatile("s_waitcnt vmcnt(0)" ::: "memory");
                char* nb = wbuf + ((s + 1) & 1) * 16384;
                *(uint4*)(nb + t * 16) = rB0;
                *(uint4*)(nb + 8192 + t * 16) = rB1;
                asm volatile("s_waitcnt lgkmcnt(0)" ::: "memory");
            }
            __builtin_amdgcn_s_barrier();
        }
    }
}

__device__ __forceinline__ void zero32(f32x16 (&acc)[2][4]) {
#pragma unroll
    for (int rr = 0; rr < 2; ++rr)
#pragma unroll
        for (int cc = 0; cc < 4; ++cc)
#pragma unroll
            for (int i = 0; i < 16; ++i) acc[rr][cc][i] = 0.f;
}

template<bool RELU>
__device__ __forceinline__ void epi_lds32(const f32x16 (&acc)[2][4], const float* __restrict__ bias,
    bf16_t* act, int wm, int wn, int l31, int kg)
{
#pragma unroll
    for (int cc = 0; cc < 4; ++cc)
#pragma unroll
    for (int q = 0; q < 4; ++q) {
        const int c0 = wn * 128 + cc * 32 + q * 8 + kg * 4;
        float4 b4 = *(const float4*)(bias + c0);
#pragma unroll
        for (int rr = 0; rr < 2; ++rr) {
            float v0 = acc[rr][cc][q * 4 + 0] + b4.x;
            float v1 = acc[rr][cc][q * 4 + 1] + b4.y;
            float v2 = acc[rr][cc][q * 4 + 2] + b4.z;
            float v3 = acc[rr][cc][q * 4 + 3] + b4.w;
            if (RELU) {
                v0 = fmaxf(v0, 0.f); v1 = fmaxf(v1, 0.f);
                v2 = fmaxf(v2, 0.f); v3 = fmaxf(v3, 0.f);
            }
            bf16x4 p = { (bf16_t)v0, (bf16_t)v1, (bf16_t)v2, (bf16_t)v3 };
            *(bf16x4*)((char*)act + act_off(wm * 64 + rr * 32 + l31, c0 * 2)) = p;
        }
    }
}
__device__ __forceinline__ void epi_global32(const f32x16 (&acc)[2][4], const float* __restrict__ bias,
    float* __restrict__ out, long r0, int wm, int wn, int l31, int kg)
{
#pragma unroll
    for (int cc = 0; cc < 4; ++cc)
#pragma unroll
    for (int q = 0; q < 4; ++q) {
        const int c0 = wn * 128 + cc * 32 + q * 8 + kg * 4;
        float4 b4 = *(const float4*)(bias + c0);
#pragma unroll
        for (int rr = 0; rr < 2; ++rr) {
            float4 o = { acc[rr][cc][q * 4 + 0] + b4.x, acc[rr][cc][q * 4 + 1] + b4.y,
                         acc[rr][cc][q * 4 + 2] + b4.z, acc[rr][cc][q * 4 + 3] + b4.w };
            *(float4*)(out + (r0 + wm * 64 + rr * 32 + l31) * 512 + c0) = o;
        }
    }
}

// ---------- kernel 1: cast + retile weights (enc: BK=32 layout, dec: BK=16 layout) ----------
__device__ __forceinline__ void decode32(int m, int& n, int& k) {   // [tile32k][kg4][col][8]
    int s = m >> 14, r = m & 16383;
    int kg = r >> 12, q = r & 4095;
    n = q >> 3;
    k = (s << 5) + (kg << 3) + (q & 7);
}
__device__ __forceinline__ void decode16(int m, int& n, int& k) {   // [tile8k][kg2][col][8]
    int s = m >> 13, r = m & 8191;
    int kg = r >> 12, q = r & 4095;
    n = q >> 3;
    k = (s << 4) + (kg << 3) + (q & 7);
}
__global__ __launch_bounds__(256) void cast_kernel(
    const float* __restrict__ W1, const float* __restrict__ W2,
    const float* __restrict__ muW, const float* __restrict__ lvW,
    const float* __restrict__ Wqkv, const float* __restrict__ Wo,
    const float* __restrict__ Wc, const float* __restrict__ Wd1,
    const float* __restrict__ Wd2, const float* __restrict__ Wd3,
    bf16_t* __restrict__ dst)
{
    int i = blockIdx.x * 256 + threadIdx.x;   // grid exactly covers 1376256
    float val;
    int n, k;
    if (i < 262144) {
        decode32(i, n, k);                    val = W1[n * 512 + k];
    } else if (i < 524288) {
        decode32(i - 262144, n, k);           val = W2[n * 512 + k];
    } else if (i < 786432) {
        decode32(i - 524288, n, k);
        val = (n < 256) ? muW[n * 512 + k] : lvW[(n - 256) * 512 + k];
    } else if (i < 798720) { val = Wqkv[i - 786432]; }
    else if (i < 802816)   { val = Wo[i - 798720]; }
    else if (i < 819200)   { val = Wc[i - 802816]; }
    else if (i < 851968) {
        decode16(i - 819200, n, k);           val = Wd1[n * 64 + k];
    } else if (i < 1114112) {
        decode16(i - 851968, n, k);           val = Wd2[n * 512 + k];
    } else {
        decode16(i - 1114112, n, k);          val = Wd3[n * 512 + k];
    }
    dst[i] = (bf16_t)val;
}

// ---------- kernel 2: encoder + heads + reparameterize (R9-verified structure) ----------
__global__ __launch_bounds__(512, 2) void enc_kernel(
    const float* __restrict__ x, const float* __restrict__ eps,
    const bf16_t* __restrict__ W1t, const float* __restrict__ b1,
    const bf16_t* __restrict__ W2t, const float* __restrict__ b2,
    const bf16_t* __restrict__ Ht,  const float* __restrict__ mub,
    const float* __restrict__ lvb,  bf16_t* __restrict__ zout)
{
    __shared__ bf16_t act[64 * 512];            // 64 KB
    __shared__ alignas(16) char wbuf[3 * 32768];// 96 KB
    const int t = threadIdx.x;
    const int wave = t >> 6, lane = t & 63, l15 = lane & 15, lhi = lane >> 4;
    const int n0 = wave * 64;
    const size_t r0 = (size_t)blockIdx.x * 64;

    stageW32(W1t, 0, wbuf, 0, wave, lane);
    stageW32(W1t, 1, wbuf, 1, wave, lane);

    // stage x tile (fp32 -> bf16, swizzled (row&7))
    for (int it = 0; it < 16; ++it) {
        int flat = it * 512 + t;
        int row = flat >> 7, c4 = flat & 127;
        float4 v = ((const float4*)(x + (r0 + row) * 512))[c4];
        bf16x4 h = { (bf16_t)v.x, (bf16_t)v.y, (bf16_t)v.z, (bf16_t)v.w };
        int byte = (row << 10) + (c4 << 3);
        byte ^= ((row & 7) << 4);
        *(bf16x4*)((char*)act + byte) = h;
    }
    asm volatile("s_waitcnt lgkmcnt(0)" ::: "memory");

    f32x4 acc[4][4];
    zero4(acc);
    layer_gl<16, true, 0>(acc, act, wbuf, W1t, W2t, wave, lane, n0, l15, lhi);
    __builtin_amdgcn_s_barrier();
    epi_lds16<true>(acc, b1, act, n0, l15, lhi);
    asm volatile("s_waitcnt lgkmcnt(0)" ::: "memory");
    __builtin_amdgcn_s_barrier();

    zero4(acc);
    layer_gl<16, true, 1>(acc, act, wbuf, W2t, Ht, wave, lane, n0, l15, lhi);
    __builtin_amdgcn_s_barrier();
    epi_lds16<true>(acc, b2, act, n0, l15, lhi);
    asm volatile("s_waitcnt lgkmcnt(0)" ::: "memory");
    __builtin_amdgcn_s_barrier();

    zero4(acc);
    layer_gl<16, false, 2>(acc, act, wbuf, Ht, (const bf16_t*)nullptr, wave, lane, n0, l15, lhi);
    __builtin_amdgcn_s_barrier();
    epi_lds16<false>(acc, (n0 < 256) ? (mub + 0) : (lvb - 256), act, n0, l15, lhi);
    asm volatile("s_waitcnt lgkmcnt(0)" ::: "memory");
    __builtin_amdgcn_s_barrier();

    // z = mu + eps * T^1.5 * exp(0.5*lv); mu cols 0-255, lv cols 256-511
    const int cc = (t & 63) * 4;
    const int ag = cc >> 6;
    const float tp = (ag == 0) ? 1.8371173070873836f
                   : (ag == 1) ? 0.35355339059327373f
                   : (ag == 2) ? 1.0f
                               : 0.7155417527999327f;
    const int rb = t >> 6;
    for (int it = 0; it < 8; ++it) {
        int row = it * 8 + rb;
        bf16x4 mu4 = lds_read8B(act, row, cc, 1024);
        bf16x4 lv4 = lds_read8B(act, row, cc + 256, 1024);
        float4 ep4 = *(const float4*)(eps + (r0 + row) * 256 + cc);
        bf16x4 zo;
        zo[0] = (bf16_t)fmaf(ep4.x * tp, expf(0.5f * (float)lv4[0]), (float)mu4[0]);
        zo[1] = (bf16_t)fmaf(ep4.y * tp, expf(0.5f * (float)lv4[1]), (float)mu4[1]);
        zo[2] = (bf16_t)fmaf(ep4.z * tp, expf(0.5f * (float)lv4[2]), (float)mu4[2]);
        zo[3] = (bf16_t)fmaf(ep4.w * tp, expf(0.5f * (float)lv4[3]), (float)mu4[3]);
        *(bf16x4*)(zout + (r0 + row) * 256 + cc) = zo;
    }
}

// ---------- kernel 3: attention over 4 agents + consensus (unchanged) ----------
__global__ __launch_bounds__(512) void attn_kernel(
    const bf16_t* __restrict__ z,
    const bf16_t* __restrict__ Wqkvb, const float* __restrict__ bqkv,
    const bf16_t* __restrict__ Wob,   const float* __restrict__ bo,
    const bf16_t* __restrict__ Wcb,   const float* __restrict__ bc,
    bf16_t* __restrict__ zcb)
{
    __shared__ bf16_t zt[256 * 64];    // z tile, later ctx tile   (rowB 128)
    __shared__ bf16_t qt[256 * 192];   // qkv tile, later z_att    (rowB 384/128)
    const int t = threadIdx.x;
    const size_t s0 = (size_t)blockIdx.x * 64;

    for (int it = 0; it < 4; ++it) {
        int ch = it * 512 + t;
        int r = ch >> 3, cc = ch & 7;
        bf16x8 v = *(const bf16x8*)(z + s0 * 256 + r * 64 + cc * 8);
        lds_write16B(zt, r, cc * 16, 128, v);
    }
    __syncthreads();
    const int wave = t >> 6, lane = t & 63, l15 = lane & 15, lhi = lane >> 4;
    const int rbase = wave * 32;

    for (int cc = 0; cc < 4; ++cc) {
        f32x4 acc[2][3] = {};
#pragma unroll
        for (int ks = 0; ks < 2; ++ks) {
            int k = ks * 32 + lhi * 8;
            bf16x8 a0 = lds_read8(zt, rbase + l15, k, 128);
            bf16x8 a1 = lds_read8(zt, rbase + 16 + l15, k, 128);
#pragma unroll
            for (int cf = 0; cf < 3; ++cf) {
                bf16x8 b = *(const bf16x8*)(Wqkvb + (cc * 48 + cf * 16 + l15) * 64 + k);
                acc[0][cf] = MFMA16(a0, b, acc[0][cf]);
                acc[1][cf] = MFMA16(a1, b, acc[1][cf]);
            }
        }
#pragma unroll
        for (int cf = 0; cf < 3; ++cf) {
            int col = cc * 48 + cf * 16 + l15;
            float bs = bqkv[col];
#pragma unroll
            for (int rf = 0; rf < 2; ++rf)
#pragma unroll
                for (int r = 0; r < 4; ++r)
                    lds_write1(qt, rbase + rf * 16 + lhi * 4 + r, col, 384, acc[rf][cf][r] + bs);
        }
    }
    __syncthreads();

    if (t < 256) {
        const int sl = t >> 2, head = t & 3;
        bf16x8 qv[4][2], kv[4][2], vv[4][2];
#pragma unroll
        for (int a2 = 0; a2 < 4; ++a2) {
            int r = sl * 4 + a2;
#pragma unroll
            for (int i = 0; i < 2; ++i) {
                qv[a2][i] = lds_read16B(qt, r, head * 32 + 16 * i, 384);
                kv[a2][i] = lds_read16B(qt, r, 128 + head * 32 + 16 * i, 384);
                vv[a2][i] = lds_read16B(qt, r, 256 + head * 32 + 16 * i, 384);
            }
        }
        float sc[4][4];
#pragma unroll
        for (int qa = 0; qa < 4; ++qa)
#pragma unroll
            for (int ka = 0; ka < 4; ++ka) {
                float s = 0.f;
#pragma unroll
                for (int i = 0; i < 2; ++i)
#pragma unroll
                    for (int j = 0; j < 8; ++j)
                        s += (float)qv[qa][i][j] * (float)kv[ka][i][j];
                sc[qa][ka] = s * 0.25f;
            }
#pragma unroll
        for (int qa = 0; qa < 4; ++qa) {
            float m = fmaxf(fmaxf(sc[qa][0], sc[qa][1]), fmaxf(sc[qa][2], sc[qa][3]));
            float e[4], sum = 0.f;
#pragma unroll
            for (int ka = 0; ka < 4; ++ka) { e[ka] = expf(sc[qa][ka] - m); sum += e[ka]; }
            float inv = 1.f / sum;
#pragma unroll
            for (int i = 0; i < 2; ++i) {
                bf16x8 cv;
#pragma unroll
                for (int j = 0; j < 8; ++j) {
                    float cval = 0.f;
#pragma unroll
                    for (int ka = 0; ka < 4; ++ka) cval += e[ka] * inv * (float)vv[ka][i][j];
                    cv[j] = (bf16_t)cval;
                }
                lds_write16B(zt, sl * 4 + qa, head * 32 + 16 * i, 128, cv);
            }
        }
    }
    __syncthreads();

    {   // z_att = ctx @ Wo^T + bo
        f32x4 acc[2][4] = {};
#pragma unroll
        for (int ks = 0; ks < 2; ++ks) {
            int k = ks * 32 + lhi * 8;
            bf16x8 a0 = lds_read8(zt, rbase + l15, k, 128);
            bf16x8 a1 = lds_read8(zt, rbase + 16 + l15, k, 128);
#pragma unroll
            for (int cf = 0; cf < 4; ++cf) {
                bf16x8 b = *(const bf16x8*)(Wob + (cf * 16 + l15) * 64 + k);
                acc[0][cf] = MFMA16(a0, b, acc[0][cf]);
                acc[1][cf] = MFMA16(a1, b, acc[1][cf]);
            }
        }
        __syncthreads();
#pragma unroll
        for (int cf = 0; cf < 4; ++cf) {
            int col = cf * 16 + l15;
            float bs = bo[col];
#pragma unroll
            for (int rf = 0; rf < 2; ++rf)
#pragma unroll
                for (int r = 0; r < 4; ++r)
                    lds_write1(qt, rbase + rf * 16 + lhi * 4 + r, col, 128, acc[rf][cf][r] + bs);
        }
    }
    __syncthreads();

    {   // z_consensus = z_att.reshape(64,256) @ Wc^T + bc
        f32x4 acc2[2] = {};
        const int rfw = wave >> 1, cbase = (wave & 1) * 2;
        const int srow = rfw * 16 + l15;
#pragma unroll
        for (int ks = 0; ks < 8; ++ks) {
            int k = ks * 32 + lhi * 8;
            int byte = (srow << 9) + (k << 1);
            byte ^= ((((srow << 2) + (k >> 6)) & 7) << 4);
            bf16x8 a = *(const bf16x8*)((const char*)qt + byte);
#pragma unroll
            for (int i = 0; i < 2; ++i) {
                bf16x8 b = *(const bf16x8*)(Wcb + ((cbase + i) * 16 + l15) * 256 + k);
                acc2[i] = MFMA16(a, b, acc2[i]);
            }
        }
#pragma unroll
        for (int i = 0; i < 2; ++i) {
            int col = (cbase + i) * 16 + l15;
            float bs = bc[col];
#pragma unroll
            for (int r = 0; r < 4; ++r) {
                int s = (int)(s0) + rfw * 16 + lhi * 4 + r;
                zcb[(size_t)s * 64 + col] = (bf16_t)(acc2[i][r] + bs);
            }
        }
    }
}

// ---------- kernel 4: fused 3-layer decoder (128-row reg-staged, 1 barrier/step) ----------
__global__ __launch_bounds__(512, 2) void dec_kernel(
    const bf16_t* __restrict__ z, const bf16_t* __restrict__ zc,
    const bf16_t* __restrict__ Wd1t, const float* __restrict__ bd1,
    const bf16_t* __restrict__ Wd2t, const float* __restrict__ bd2,
    const bf16_t* __restrict__ Wd3t, const float* __restrict__ bd3,
    float* __restrict__ out)
{
    __shared__ bf16_t act[128 * 512];            // 128 KB (latents in cols 0..63)
    __shared__ alignas(16) char wbuf[2 * 16384]; // 32 KB ping-pong
    const int t = threadIdx.x;
    const int wave = t >> 6, lane = t & 63, l31 = lane & 31, kg = lane >> 5;
    const int wm = wave >> 2, wn = wave & 3;
    const long r0 = (long)blockIdx.x * 128;

    // gather latent rows into act cols 0..63: row = s*5 + j
    for (int it = 0; it < 2; ++it) {
        int flat = it * 512 + t;
        int row = flat >> 3, ch = flat & 7;
        long rg = r0 + row;
        int s5 = (int)(rg / 5), j = (int)(rg - (long)s5 * 5);
        const bf16_t* src = (j == 0) ? (zc + (size_t)s5 * 64)
                                     : (z + (size_t)s5 * 256 + (j - 1) * 64);
        bf16x8 v = *(const bf16x8*)(src + ch * 8);
        *(bf16x8*)((char*)act + act_off(row, ch * 16)) = v;
    }
    asm volatile("s_waitcnt lgkmcnt(0)" ::: "memory");

    f32x16 acc[2][4];
    zero32(acc);
    layer_rs<4>(acc, act, wbuf, Wd1t, t, wave, lane, wm, wn, l31, kg);
    epi_lds32<true>(acc, bd1, act, wm, wn, l31, kg);
    asm volatile("s_waitcnt lgkmcnt(0)" ::: "memory");
    __builtin_amdgcn_s_barrier();

    zero32(acc);
    layer_rs<32>(acc, act, wbuf, Wd2t, t, wave, lane, wm, wn, l31, kg);
    epi_lds32<true>(acc, bd2, act, wm, wn, l31, kg);
    asm volatile("s_waitcnt lgkmcnt(0)" ::: "memory");
    __builtin_amdgcn_s_barrier();

    zero32(acc);
    layer_rs<32>(acc, act, wbuf, Wd3t, t, wave, lane, wm, wn, l31, kg);
    epi_global32(acc, bd3, out, r0, wm, wn, l31, kg);
}

// ---------- launcher ----------
extern "C" void kernel_launch(void* const* d_in, const int* in_sizes, int n_in,
                              void* d_out, int out_size, void* d_ws, size_t ws_size,
                              hipStream_t stream) {
    const float* x    = (const float*)d_in[0];
    const float* eps  = (const float*)d_in[1];
    const float* W1   = (const float*)d_in[2];
    const float* b1   = (const float*)d_in[3];
    const float* W2   = (const float*)d_in[4];
    const float* b2   = (const float*)d_in[5];
    const float* muW  = (const float*)d_in[6];
    const float* mub  = (const float*)d_in[7];
    const float* lvW  = (const float*)d_in[8];
    const float* lvb  = (const float*)d_in[9];
    const float* Wqkv = (const float*)d_in[10];
    const float* bqkv = (const float*)d_in[11];
    const float* Wo   = (const float*)d_in[12];
    const float* bo   = (const float*)d_in[13];
    const float* Wc   = (const float*)d_in[14];
    const float* bc   = (const float*)d_in[15];
    const float* Wd1  = (const float*)d_in[16];
    const float* bd1  = (const float*)d_in[17];
    const float* Wd2  = (const float*)d_in[18];
    const float* bd2  = (const float*)d_in[19];
    const float* Wd3  = (const float*)d_in[20];
    const float* bd3  = (const float*)d_in[21];
    float* out = (float*)d_out;

    bf16_t* wsb  = (bf16_t*)d_ws;
    bf16_t* W1t  = wsb + 0;
    bf16_t* W2t  = wsb + 262144;
    bf16_t* Ht   = wsb + 524288;    // [muW ; lvW] retiled (BK=32)
    bf16_t* Wqkvb= wsb + 786432;
    bf16_t* Wob  = wsb + 798720;
    bf16_t* Wcb  = wsb + 802816;
    bf16_t* Wd1t = wsb + 819200;    // BK=16
    bf16_t* Wd2t = wsb + 851968;
    bf16_t* Wd3t = wsb + 1114112;
    bf16_t* zbuf = wsb + 1376256;   // (B,256) bf16
    bf16_t* zcb  = wsb + 9764864;   // (B,64)  bf16

    cast_kernel<<<dim3(5376), dim3(256), 0, stream>>>(
        W1, W2, muW, lvW, Wqkv, Wo, Wc, Wd1, Wd2, Wd3, wsb);
    enc_kernel<<<dim3(512), dim3(512), 0, stream>>>(
        x, eps, W1t, b1, W2t, b2, Ht, mub, lvb, zbuf);
    attn_kernel<<<dim3(512), dim3(512), 0, stream>>>(
        zbuf, Wqkvb, bqkv, Wob, bo, Wcb, bc, zcb);
    dec_kernel<<<dim3(1280), dim3(512), 0, stream>>>(
        zbuf, zcb, Wd1t, bd1, Wd2t, bd2, Wd3t, bd3, out);
}

// Round 19
// 351.996 us; speedup vs baseline: 1.5575x; 1.0817x over previous
//
#include <hip/hip_runtime.h>

typedef __bf16 bf16_t;
typedef __bf16 bf16x8 __attribute__((ext_vector_type(8)));
typedef __bf16 bf16x4 __attribute__((ext_vector_type(4)));
typedef float  f32x4  __attribute__((ext_vector_type(4)));
typedef float  f32x16 __attribute__((ext_vector_type(16)));

#define MFMA16(a,b,c) __builtin_amdgcn_mfma_f32_16x16x32_bf16((a),(b),(c),0,0,0)
#define MFMA32(a,b,c) __builtin_amdgcn_mfma_f32_32x32x16_bf16((a),(b),(c),0,0,0)
#define GLOBAL_AS __attribute__((address_space(1)))
#define LDS_AS    __attribute__((address_space(3)))

// ---------- act LDS for dec: [128][512] bf16, XOR swizzle (row&15)<<4 ----------
__device__ __forceinline__ int act_off(int row, int kByte) {
    int byte = (row << 10) + kByte;
    return byte ^ ((row & 15) << 4);
}

// ---------- legacy swizzled helpers ((row&7)<<4) — enc R9 path + attn ----------
__device__ __forceinline__ bf16x8 lds_read8(const bf16_t* base, int row, int k, int rowB) {
    int byte = row * rowB + (k << 1);
    byte ^= ((row & 7) << 4);
    return *(const bf16x8*)((const char*)base + byte);
}
__device__ __forceinline__ void lds_write8B(bf16_t* base, int row, int col, int rowB, bf16x4 v) {
    int byte = row * rowB + (col << 1);
    byte ^= ((row & 7) << 4);
    *(bf16x4*)((char*)base + byte) = v;
}
__device__ __forceinline__ bf16x4 lds_read8B(const bf16_t* base, int row, int col, int rowB) {
    int byte = row * rowB + (col << 1);
    byte ^= ((row & 7) << 4);
    return *(const bf16x4*)((const char*)base + byte);
}
__device__ __forceinline__ void lds_write1(bf16_t* base, int row, int col, int rowB, float v) {
    int byte = row * rowB + (col << 1);
    byte ^= ((row & 7) << 4);
    *(bf16_t*)((char*)base + byte) = (bf16_t)v;
}
__device__ __forceinline__ void lds_write16B(bf16_t* base, int row, int colbyte, int rowB, bf16x8 v) {
    int byte = row * rowB + colbyte;
    byte ^= ((row & 7) << 4);
    *(bf16x8*)((char*)base + byte) = v;
}
__device__ __forceinline__ bf16x8 lds_read16B(const bf16_t* base, int row, int colbyte, int rowB) {
    int byte = row * rowB + colbyte;
    byte ^= ((row & 7) << 4);
    return *(const bf16x8*)((const char*)base + byte);
}

__device__ __forceinline__ void gload_lds16(const void* g, void* l) {
    __builtin_amdgcn_global_load_lds((const GLOBAL_AS void*)g, (LDS_AS void*)l, 16, 0, 0);
}

// =================== ENC engine (R9-verified): BK=32 tiles, 3 gload buffers ===================
// W tile 32KB: [kg(4)][col(512)][16B] -> element (col, k = tile*32 + kg*8 + e)
__device__ __forceinline__ void stageW32(const bf16_t* __restrict__ Wt, int tile,
                                         char* wbuf, int bufIdx, int wave, int lane) {
    const char* s = (const char*)Wt + (size_t)tile * 32768 + wave * 4096 + lane * 16;
    char* d = wbuf + bufIdx * 32768 + wave * 4096;
#pragma unroll
    for (int c = 0; c < 4; ++c)
        gload_lds16(s + c * 1024, d + c * 1024);
}

// per-wave tile 64x64, MFMA16 acc[4][4]: C[row=rf*16+l15][col=n0+cf*16+lhi*4+r]
template<int NS, bool CONT, int TB>
__device__ __forceinline__ void layer_gl(f32x4 (&acc)[4][4],
    const bf16_t* act, char* wbuf,
    const bf16_t* __restrict__ Wt, const bf16_t* __restrict__ Wn,
    int wave, int lane, int n0, int l15, int lhi)
{
#pragma unroll
    for (int s = 0; s < NS; ++s) {
        if (s == NS - 1 && !CONT) {
            asm volatile("s_waitcnt vmcnt(0)" ::: "memory");
        } else {
            asm volatile("s_waitcnt vmcnt(4)" ::: "memory");
        }
        __builtin_amdgcn_s_barrier();
        if (s + 2 < NS)  stageW32(Wt, s + 2,      wbuf, (TB + s + 2) % 3, wave, lane);
        else if (CONT)   stageW32(Wn, s + 2 - NS, wbuf, (TB + s + 2) % 3, wave, lane);
        const char* bb = wbuf + ((TB + s) % 3) * 32768 + lhi * 8192;
        bf16x8 a[4], b[4];
#pragma unroll
        for (int cf = 0; cf < 4; ++cf)
            b[cf] = *(const bf16x8*)(bb + (n0 + cf * 16 + l15) * 16);
#pragma unroll
        for (int rf = 0; rf < 4; ++rf)
            a[rf] = lds_read8(act, rf * 16 + l15, s * 32 + lhi * 8, 1024);
#pragma unroll
        for (int rf = 0; rf < 4; ++rf)
#pragma unroll
            for (int cf = 0; cf < 4; ++cf)
                acc[rf][cf] = MFMA16(b[cf], a[rf], acc[rf][cf]);
    }
}

__device__ __forceinline__ void zero4(f32x4 (&acc)[4][4]) {
#pragma unroll
    for (int rf = 0; rf < 4; ++rf)
#pragma unroll
        for (int cf = 0; cf < 4; ++cf)
            acc[rf][cf] = f32x4{0.f, 0.f, 0.f, 0.f};
}

template<bool RELU>
__device__ __forceinline__ void epi_lds16(const f32x4 (&acc)[4][4], const float* __restrict__ bias,
    bf16_t* dst, int n0, int l15, int lhi)
{
#pragma unroll
    for (int cf = 0; cf < 4; ++cf) {
        const int c0 = n0 + cf * 16 + lhi * 4;
        float4 b4 = *(const float4*)(bias + c0);
#pragma unroll
        for (int rf = 0; rf < 4; ++rf) {
            float v0 = acc[rf][cf][0] + b4.x;
            float v1 = acc[rf][cf][1] + b4.y;
            float v2 = acc[rf][cf][2] + b4.z;
            float v3 = acc[rf][cf][3] + b4.w;
            if (RELU) {
                v0 = fmaxf(v0, 0.f); v1 = fmaxf(v1, 0.f);
                v2 = fmaxf(v2, 0.f); v3 = fmaxf(v3, 0.f);
            }
            bf16x4 p = { (bf16_t)v0, (bf16_t)v1, (bf16_t)v2, (bf16_t)v3 };
            lds_write8B(dst, rf * 16 + l15, c0, 1024, p);
        }
    }
}

// =================== DEC engine: barrier-free per-wave register streaming ===================
// W tile 16KB: [wn(4)][cc(4)][lane(64)][16B]:
//   element (col = wn*128 + cc*32 + (lane&31), k = tile*16 + (lane>>5)*8 + j)
// Wave (wm,wn) step s reads 4 contiguous 1KB chunks at tile*16384 + wn*4096 + cc*1024 + lane*16.
// Fully coalesced; b[cc] IS the MFMA B-fragment (identical content to R18's LDS path).
__device__ __forceinline__ void dec_mfma(f32x16 (&acc)[2][4],
    const bf16_t* act, const bf16x8 (&b)[4], int s, int wm, int l31, int kg)
{
    bf16x8 a[2];
#pragma unroll
    for (int rr = 0; rr < 2; ++rr)
        a[rr] = *(const bf16x8*)((const char*)act +
                    act_off(wm * 64 + rr * 32 + l31, s * 32 + kg * 16));
#pragma unroll
    for (int rr = 0; rr < 2; ++rr)
#pragma unroll
        for (int cc = 0; cc < 4; ++cc)
            acc[rr][cc] = MFMA32(b[cc], a[rr], acc[rr][cc]);
}

template<int NS>
__device__ __forceinline__ void layer_reg(f32x16 (&acc)[2][4],
    const bf16_t* act, const bf16_t* __restrict__ Wt,
    int lane, int wm, int wn, int l31, int kg)
{
    const char* gb = (const char*)Wt + wn * 4096 + lane * 16;
    bf16x8 pA[4], pB[4];
#pragma unroll
    for (int c = 0; c < 4; ++c) pA[c] = *(const bf16x8*)(gb + c * 1024);
#pragma unroll
    for (int c = 0; c < 4; ++c) pB[c] = *(const bf16x8*)(gb + 16384 + c * 1024);
#pragma unroll
    for (int p = 0; p < NS / 2; ++p) {
        {   // s = 2p: consume pA, refill pA with tile s+2
            const int s = 2 * p;
            bf16x8 b[4];
#pragma unroll
            for (int c = 0; c < 4; ++c) b[c] = pA[c];
            if (s + 2 < NS) {
#pragma unroll
                for (int c = 0; c < 4; ++c)
                    pA[c] = *(const bf16x8*)(gb + (size_t)(s + 2) * 16384 + c * 1024);
            }
            dec_mfma(acc, act, b, s, wm, l31, kg);
        }
        {   // s = 2p+1: consume pB, refill pB with tile s+2
            const int s = 2 * p + 1;
            bf16x8 b[4];
#pragma unroll
            for (int c = 0; c < 4; ++c) b[c] = pB[c];
            if (s + 2 < NS) {
#pragma unroll
                for (int c = 0; c < 4; ++c)
                    pB[c] = *(const bf16x8*)(gb + (size_t)(s + 2) * 16384 + c * 1024);
            }
            dec_mfma(acc, act, b, s, wm, l31, kg);
        }
    }
}

__device__ __forceinline__ void zero32(f32x16 (&acc)[2][4]) {
#pragma unroll
    for (int rr = 0; rr < 2; ++rr)
#pragma unroll
        for (int cc = 0; cc < 4; ++cc)
#pragma unroll
            for (int i = 0; i < 16; ++i) acc[rr][cc][i] = 0.f;
}

template<bool RELU>
__device__ __forceinline__ void epi_lds32(const f32x16 (&acc)[2][4], const float* __restrict__ bias,
    bf16_t* act, int wm, int wn, int l31, int kg)
{
#pragma unroll
    for (int cc = 0; cc < 4; ++cc)
#pragma unroll
    for (int q = 0; q < 4; ++q) {
        const int c0 = wn * 128 + cc * 32 + q * 8 + kg * 4;
        float4 b4 = *(const float4*)(bias + c0);
#pragma unroll
        for (int rr = 0; rr < 2; ++rr) {
            float v0 = acc[rr][cc][q * 4 + 0] + b4.x;
            float v1 = acc[rr][cc][q * 4 + 1] + b4.y;
            float v2 = acc[rr][cc][q * 4 + 2] + b4.z;
            float v3 = acc[rr][cc][q * 4 + 3] + b4.w;
            if (RELU) {
                v0 = fmaxf(v0, 0.f); v1 = fmaxf(v1, 0.f);
                v2 = fmaxf(v2, 0.f); v3 = fmaxf(v3, 0.f);
            }
            bf16x4 p = { (bf16_t)v0, (bf16_t)v1, (bf16_t)v2, (bf16_t)v3 };
            *(bf16x4*)((char*)act + act_off(wm * 64 + rr * 32 + l31, c0 * 2)) = p;
        }
    }
}
__device__ __forceinline__ void epi_global32(const f32x16 (&acc)[2][4], const float* __restrict__ bias,
    float* __restrict__ out, long r0, int wm, int wn, int l31, int kg)
{
#pragma unroll
    for (int cc = 0; cc < 4; ++cc)
#pragma unroll
    for (int q = 0; q < 4; ++q) {
        const int c0 = wn * 128 + cc * 32 + q * 8 + kg * 4;
        float4 b4 = *(const float4*)(bias + c0);
#pragma unroll
        for (int rr = 0; rr < 2; ++rr) {
            float4 o = { acc[rr][cc][q * 4 + 0] + b4.x, acc[rr][cc][q * 4 + 1] + b4.y,
                         acc[rr][cc][q * 4 + 2] + b4.z, acc[rr][cc][q * 4 + 3] + b4.w };
            *(float4*)(out + (r0 + wm * 64 + rr * 32 + l31) * 512 + c0) = o;
        }
    }
}

// ---------- kernel 1: cast + retile weights ----------
// enc: BK=32 layout [tile][kg4][col][8elem]; dec: per-wave reg layout (above)
__device__ __forceinline__ void decode32(int m, int& n, int& k) {
    int s = m >> 14, r = m & 16383;
    int kg = r >> 12, q = r & 4095;
    n = q >> 3;
    k = (s << 5) + (kg << 3) + (q & 7);
}
__device__ __forceinline__ void decode_reg(int m, int& n, int& k) {
    int tile = m >> 13, e = m & 8191;
    int wn = e >> 11, c = (e >> 9) & 3, ln = (e >> 3) & 63, j = e & 7;
    n = wn * 128 + c * 32 + (ln & 31);
    k = (tile << 4) + ((ln >> 5) << 3) + j;
}
__global__ __launch_bounds__(256) void cast_kernel(
    const float* __restrict__ W1, const float* __restrict__ W2,
    const float* __restrict__ muW, const float* __restrict__ lvW,
    const float* __restrict__ Wqkv, const float* __restrict__ Wo,
    const float* __restrict__ Wc, const float* __restrict__ Wd1,
    const float* __restrict__ Wd2, const float* __restrict__ Wd3,
    bf16_t* __restrict__ dst)
{
    int i = blockIdx.x * 256 + threadIdx.x;   // grid exactly covers 1376256
    float val;
    int n, k;
    if (i < 262144) {
        decode32(i, n, k);                    val = W1[n * 512 + k];
    } else if (i < 524288) {
        decode32(i - 262144, n, k);           val = W2[n * 512 + k];
    } else if (i < 786432) {
        decode32(i - 524288, n, k);
        val = (n < 256) ? muW[n * 512 + k] : lvW[(n - 256) * 512 + k];
    } else if (i < 798720) { val = Wqkv[i - 786432]; }
    else if (i < 802816)   { val = Wo[i - 798720]; }
    else if (i < 819200)   { val = Wc[i - 802816]; }
    else if (i < 851968) {
        decode_reg(i - 819200, n, k);         val = Wd1[n * 64 + k];
    } else if (i < 1114112) {
        decode_reg(i - 851968, n, k);         val = Wd2[n * 512 + k];
    } else {
        decode_reg(i - 1114112, n, k);        val = Wd3[n * 512 + k];
    }
    dst[i] = (bf16_t)val;
}

// ---------- kernel 2: encoder + heads + reparameterize (R9-verified structure) ----------
__global__ __launch_bounds__(512, 2) void enc_kernel(
    const float* __restrict__ x, const float* __restrict__ eps,
    const bf16_t* __restrict__ W1t, const float* __restrict__ b1,
    const bf16_t* __restrict__ W2t, const float* __restrict__ b2,
    const bf16_t* __restrict__ Ht,  const float* __restrict__ mub,
    const float* __restrict__ lvb,  bf16_t* __restrict__ zout)
{
    __shared__ bf16_t act[64 * 512];            // 64 KB
    __shared__ alignas(16) char wbuf[3 * 32768];// 96 KB
    const int t = threadIdx.x;
    const int wave = t >> 6, lane = t & 63, l15 = lane & 15, lhi = lane >> 4;
    const int n0 = wave * 64;
    const size_t r0 = (size_t)blockIdx.x * 64;

    stageW32(W1t, 0, wbuf, 0, wave, lane);
    stageW32(W1t, 1, wbuf, 1, wave, lane);

    // stage x tile (fp32 -> bf16, swizzled (row&7))
    for (int it = 0; it < 16; ++it) {
        int flat = it * 512 + t;
        int row = flat >> 7, c4 = flat & 127;
        float4 v = ((const float4*)(x + (r0 + row) * 512))[c4];
        bf16x4 h = { (bf16_t)v.x, (bf16_t)v.y, (bf16_t)v.z, (bf16_t)v.w };
        int byte = (row << 10) + (c4 << 3);
        byte ^= ((row & 7) << 4);
        *(bf16x4*)((char*)act + byte) = h;
    }
    asm volatile("s_waitcnt lgkmcnt(0)" ::: "memory");

    f32x4 acc[4][4];
    zero4(acc);
    layer_gl<16, true, 0>(acc, act, wbuf, W1t, W2t, wave, lane, n0, l15, lhi);
    __builtin_amdgcn_s_barrier();
    epi_lds16<true>(acc, b1, act, n0, l15, lhi);
    asm volatile("s_waitcnt lgkmcnt(0)" ::: "memory");
    __builtin_amdgcn_s_barrier();

    zero4(acc);
    layer_gl<16, true, 1>(acc, act, wbuf, W2t, Ht, wave, lane, n0, l15, lhi);
    __builtin_amdgcn_s_barrier();
    epi_lds16<true>(acc, b2, act, n0, l15, lhi);
    asm volatile("s_waitcnt lgkmcnt(0)" ::: "memory");
    __builtin_amdgcn_s_barrier();

    zero4(acc);
    layer_gl<16, false, 2>(acc, act, wbuf, Ht, (const bf16_t*)nullptr, wave, lane, n0, l15, lhi);
    __builtin_amdgcn_s_barrier();
    epi_lds16<false>(acc, (n0 < 256) ? (mub + 0) : (lvb - 256), act, n0, l15, lhi);
    asm volatile("s_waitcnt lgkmcnt(0)" ::: "memory");
    __builtin_amdgcn_s_barrier();

    // z = mu + eps * T^1.5 * exp(0.5*lv); mu cols 0-255, lv cols 256-511
    const int cc = (t & 63) * 4;
    const int ag = cc >> 6;
    const float tp = (ag == 0) ? 1.8371173070873836f
                   : (ag == 1) ? 0.35355339059327373f
                   : (ag == 2) ? 1.0f
                               : 0.7155417527999327f;
    const int rb = t >> 6;
    for (int it = 0; it < 8; ++it) {
        int row = it * 8 + rb;
        bf16x4 mu4 = lds_read8B(act, row, cc, 1024);
        bf16x4 lv4 = lds_read8B(act, row, cc + 256, 1024);
        float4 ep4 = *(const float4*)(eps + (r0 + row) * 256 + cc);
        bf16x4 zo;
        zo[0] = (bf16_t)fmaf(ep4.x * tp, expf(0.5f * (float)lv4[0]), (float)mu4[0]);
        zo[1] = (bf16_t)fmaf(ep4.y * tp, expf(0.5f * (float)lv4[1]), (float)mu4[1]);
        zo[2] = (bf16_t)fmaf(ep4.z * tp, expf(0.5f * (float)lv4[2]), (float)mu4[2]);
        zo[3] = (bf16_t)fmaf(ep4.w * tp, expf(0.5f * (float)lv4[3]), (float)mu4[3]);
        *(bf16x4*)(zout + (r0 + row) * 256 + cc) = zo;
    }
}

// ---------- kernel 3: attention over 4 agents + consensus (unchanged) ----------
__global__ __launch_bounds__(512) void attn_kernel(
    const bf16_t* __restrict__ z,
    const bf16_t* __restrict__ Wqkvb, const float* __restrict__ bqkv,
    const bf16_t* __restrict__ Wob,   const float* __restrict__ bo,
    const bf16_t* __restrict__ Wcb,   const float* __restrict__ bc,
    bf16_t* __restrict__ zcb)
{
    __shared__ bf16_t zt[256 * 64];    // z tile, later ctx tile   (rowB 128)
    __shared__ bf16_t qt[256 * 192];   // qkv tile, later z_att    (rowB 384/128)
    const int t = threadIdx.x;
    const size_t s0 = (size_t)blockIdx.x * 64;

    for (int it = 0; it < 4; ++it) {
        int ch = it * 512 + t;
        int r = ch >> 3, cc = ch & 7;
        bf16x8 v = *(const bf16x8*)(z + s0 * 256 + r * 64 + cc * 8);
        lds_write16B(zt, r, cc * 16, 128, v);
    }
    __syncthreads();
    const int wave = t >> 6, lane = t & 63, l15 = lane & 15, lhi = lane >> 4;
    const int rbase = wave * 32;

    for (int cc = 0; cc < 4; ++cc) {
        f32x4 acc[2][3] = {};
#pragma unroll
        for (int ks = 0; ks < 2; ++ks) {
            int k = ks * 32 + lhi * 8;
            bf16x8 a0 = lds_read8(zt, rbase + l15, k, 128);
            bf16x8 a1 = lds_read8(zt, rbase + 16 + l15, k, 128);
#pragma unroll
            for (int cf = 0; cf < 3; ++cf) {
                bf16x8 b = *(const bf16x8*)(Wqkvb + (cc * 48 + cf * 16 + l15) * 64 + k);
                acc[0][cf] = MFMA16(a0, b, acc[0][cf]);
                acc[1][cf] = MFMA16(a1, b, acc[1][cf]);
            }
        }
#pragma unroll
        for (int cf = 0; cf < 3; ++cf) {
            int col = cc * 48 + cf * 16 + l15;
            float bs = bqkv[col];
#pragma unroll
            for (int rf = 0; rf < 2; ++rf)
#pragma unroll
                for (int r = 0; r < 4; ++r)
                    lds_write1(qt, rbase + rf * 16 + lhi * 4 + r, col, 384, acc[rf][cf][r] + bs);
        }
    }
    __syncthreads();

    if (t < 256) {
        const int sl = t >> 2, head = t & 3;
        bf16x8 qv[4][2], kv[4][2], vv[4][2];
#pragma unroll
        for (int a2 = 0; a2 < 4; ++a2) {
            int r = sl * 4 + a2;
#pragma unroll
            for (int i = 0; i < 2; ++i) {
                qv[a2][i] = lds_read16B(qt, r, head * 32 + 16 * i, 384);
                kv[a2][i] = lds_read16B(qt, r, 128 + head * 32 + 16 * i, 384);
                vv[a2][i] = lds_read16B(qt, r, 256 + head * 32 + 16 * i, 384);
            }
        }
        float sc[4][4];
#pragma unroll
        for (int qa = 0; qa < 4; ++qa)
#pragma unroll
            for (int ka = 0; ka < 4; ++ka) {
                float s = 0.f;
#pragma unroll
                for (int i = 0; i < 2; ++i)
#pragma unroll
                    for (int j = 0; j < 8; ++j)
                        s += (float)qv[qa][i][j] * (float)kv[ka][i][j];
                sc[qa][ka] = s * 0.25f;
            }
#pragma unroll
        for (int qa = 0; qa < 4; ++qa) {
            float m = fmaxf(fmaxf(sc[qa][0], sc[qa][1]), fmaxf(sc[qa][2], sc[qa][3]));
            float e[4], sum = 0.f;
#pragma unroll
            for (int ka = 0; ka < 4; ++ka) { e[ka] = expf(sc[qa][ka] - m); sum += e[ka]; }
            float inv = 1.f / sum;
#pragma unroll
            for (int i = 0; i < 2; ++i) {
                bf16x8 cv;
#pragma unroll
                for (int j = 0; j < 8; ++j) {
                    float cval = 0.f;
#pragma unroll
                    for (int ka = 0; ka < 4; ++ka) cval += e[ka] * inv * (float)vv[ka][i][j];
                    cv[j] = (bf16_t)cval;
                }
                lds_write16B(zt, sl * 4 + qa, head * 32 + 16 * i, 128, cv);
            }
        }
    }
    __syncthreads();

    {   // z_att = ctx @ Wo^T + bo
        f32x4 acc[2][4] = {};
#pragma unroll
        for (int ks = 0; ks < 2; ++ks) {
            int k = ks * 32 + lhi * 8;
            bf16x8 a0 = lds_read8(zt, rbase + l15, k, 128);
            bf16x8 a1 = lds_read8(zt, rbase + 16 + l15, k, 128);
#pragma unroll
            for (int cf = 0; cf < 4; ++cf) {
                bf16x8 b = *(const bf16x8*)(Wob + (cf * 16 + l15) * 64 + k);
                acc[0][cf] = MFMA16(a0, b, acc[0][cf]);
                acc[1][cf] = MFMA16(a1, b, acc[1][cf]);
            }
        }
        __syncthreads();
#pragma unroll
        for (int cf = 0; cf < 4; ++cf) {
            int col = cf * 16 + l15;
            float bs = bo[col];
#pragma unroll
            for (int rf = 0; rf < 2; ++rf)
#pragma unroll
                for (int r = 0; r < 4; ++r)
                    lds_write1(qt, rbase + rf * 16 + lhi * 4 + r, col, 128, acc[rf][cf][r] + bs);
        }
    }
    __syncthreads();

    {   // z_consensus = z_att.reshape(64,256) @ Wc^T + bc
        f32x4 acc2[2] = {};
        const int rfw = wave >> 1, cbase = (wave & 1) * 2;
        const int srow = rfw * 16 + l15;
#pragma unroll
        for (int ks = 0; ks < 8; ++ks) {
            int k = ks * 32 + lhi * 8;
            int byte = (srow << 9) + (k << 1);
            byte ^= ((((srow << 2) + (k >> 6)) & 7) << 4);
            bf16x8 a = *(const bf16x8*)((const char*)qt + byte);
#pragma unroll
            for (int i = 0; i < 2; ++i) {
                bf16x8 b = *(const bf16x8*)(Wcb + ((cbase + i) * 16 + l15) * 256 + k);
                acc2[i] = MFMA16(a, b, acc2[i]);
            }
        }
#pragma unroll
        for (int i = 0; i < 2; ++i) {
            int col = (cbase + i) * 16 + l15;
            float bs = bc[col];
#pragma unroll
            for (int r = 0; r < 4; ++r) {
                int s = (int)(s0) + rfw * 16 + lhi * 4 + r;
                zcb[(size_t)s * 64 + col] = (bf16_t)(acc2[i][r] + bs);
            }
        }
    }
}

// ---------- kernel 4: fused 3-layer decoder (barrier-free per-wave streaming) ----------
__global__ __launch_bounds__(512, 2) void dec_kernel(
    const bf16_t* __restrict__ z, const bf16_t* __restrict__ zc,
    const bf16_t* __restrict__ Wd1t, const float* __restrict__ bd1,
    const bf16_t* __restrict__ Wd2t, const float* __restrict__ bd2,
    const bf16_t* __restrict__ Wd3t, const float* __restrict__ bd3,
    float* __restrict__ out)
{
    __shared__ bf16_t act[128 * 512];            // 128 KB only
    const int t = threadIdx.x;
    const int wave = t >> 6, lane = t & 63, l31 = lane & 31, kg = lane >> 5;
    const int wm = wave >> 2, wn = wave & 3;
    const long r0 = (long)blockIdx.x * 128;

    // gather latent rows into act cols 0..63: row = s*5 + j
    for (int it = 0; it < 2; ++it) {
        int flat = it * 512 + t;
        int row = flat >> 3, ch = flat & 7;
        long rg = r0 + row;
        int s5 = (int)(rg / 5), j = (int)(rg - (long)s5 * 5);
        const bf16_t* src = (j == 0) ? (zc + (size_t)s5 * 64)
                                     : (z + (size_t)s5 * 256 + (j - 1) * 64);
        bf16x8 v = *(const bf16x8*)(src + ch * 8);
        *(bf16x8*)((char*)act + act_off(row, ch * 16)) = v;
    }
    __syncthreads();

    f32x16 acc[2][4];
    zero32(acc);
    layer_reg<4>(acc, act, Wd1t, lane, wm, wn, l31, kg);
    __builtin_amdgcn_s_barrier();              // all waves done reading latents
    epi_lds32<true>(acc, bd1, act, wm, wn, l31, kg);
    asm volatile("s_waitcnt lgkmcnt(0)" ::: "memory");
    __builtin_amdgcn_s_barrier();              // act layer-1 published

    zero32(acc);
    layer_reg<32>(acc, act, Wd2t, lane, wm, wn, l31, kg);
    __builtin_amdgcn_s_barrier();
    epi_lds32<true>(acc, bd2, act, wm, wn, l31, kg);
    asm volatile("s_waitcnt lgkmcnt(0)" ::: "memory");
    __builtin_amdgcn_s_barrier();

    zero32(acc);
    layer_reg<32>(acc, act, Wd3t, lane, wm, wn, l31, kg);
    epi_global32(acc, bd3, out, r0, wm, wn, l31, kg);
}

// ---------- launcher ----------
extern "C" void kernel_launch(void* const* d_in, const int* in_sizes, int n_in,
                              void* d_out, int out_size, void* d_ws, size_t ws_size,
                              hipStream_t stream) {
    const float* x    = (const float*)d_in[0];
    const float* eps  = (const float*)d_in[1];
    const float* W1   = (const float*)d_in[2];
    const float* b1   = (const float*)d_in[3];
    const float* W2   = (const float*)d_in[4];
    const float* b2   = (const float*)d_in[5];
    const float* muW  = (const float*)d_in[6];
    const float* mub  = (const float*)d_in[7];
    const float* lvW  = (const float*)d_in[8];
    const float* lvb  = (const float*)d_in[9];
    const float* Wqkv = (const float*)d_in[10];
    const float* bqkv = (const float*)d_in[11];
    const float* Wo   = (const float*)d_in[12];
    const float* bo   = (const float*)d_in[13];
    const float* Wc   = (const float*)d_in[14];
    const float* bc   = (const float*)d_in[15];
    const float* Wd1  = (const float*)d_in[16];
    const float* bd1  = (const float*)d_in[17];
    const float* Wd2  = (const float*)d_in[18];
    const float* bd2  = (const float*)d_in[19];
    const float* Wd3  = (const float*)d_in[20];
    const float* bd3  = (const float*)d_in[21];
    float* out = (float*)d_out;

    bf16_t* wsb  = (bf16_t*)d_ws;
    bf16_t* W1t  = wsb + 0;
    bf16_t* W2t  = wsb + 262144;
    bf16_t* Ht   = wsb + 524288;    // [muW ; lvW] retiled (BK=32)
    bf16_t* Wqkvb= wsb + 786432;
    bf16_t* Wob  = wsb + 798720;
    bf16_t* Wcb  = wsb + 802816;
    bf16_t* Wd1t = wsb + 819200;    // per-wave reg layout
    bf16_t* Wd2t = wsb + 851968;
    bf16_t* Wd3t = wsb + 1114112;
    bf16_t* zbuf = wsb + 1376256;   // (B,256) bf16
    bf16_t* zcb  = wsb + 9764864;   // (B,64)  bf16

    cast_kernel<<<dim3(5376), dim3(256), 0, stream>>>(
        W1, W2, muW, lvW, Wqkv, Wo, Wc, Wd1, Wd2, Wd3, wsb);
    enc_kernel<<<dim3(512), dim3(512), 0, stream>>>(
        x, eps, W1t, b1, W2t, b2, Ht, mub, lvb, zbuf);
    attn_kernel<<<dim3(512), dim3(512), 0, stream>>>(
        zbuf, Wqkvb, bqkv, Wob, bo, Wcb, bc, zcb);
    dec_kernel<<<dim3(1280), dim3(512), 0, stream>>>(
        zbuf, zcb, Wd1t, bd1, Wd2t, bd2, Wd3t, bd3, out);
}